// Round 9
// baseline (2971.139 us; speedup 1.0000x reference)
//
#include <hip/hip_runtime.h>
#include <hip/hip_bf16.h>
#include <stdint.h>
#include <stddef.h>

using bf16 = __hip_bfloat16;
typedef __attribute__((ext_vector_type(8))) short short8;
typedef __attribute__((ext_vector_type(4))) float f32x4;
typedef __attribute__((ext_vector_type(4))) unsigned u32x4;

constexpr int BATCH = 2048;
constexpr int NN    = 1024;
constexpr int H1C   = 3072;
constexpr int H2C   = 4096;
constexpr int CAP   = 128;   // max nnz per sparse row
constexpr int BB    = 8;     // batch columns per LDS-slice block
constexpr int NBLK  = BATCH / BB;  // 256 blocks (1 per CU)

// CSR global row offsets
constexpr int ROW_WV1 = 0;                 // 5*3072 rows, len 3072
constexpr int ROW_WO1 = 5 * H1C;           // 5*1024 rows, len 3072
constexpr int ROW_WV2 = ROW_WO1 + 5 * NN;  // 5*4096 rows, len 4096
constexpr int ROW_WO2 = ROW_WV2 + 5 * H2C; // 5*1024 rows, len 4096
constexpr int ROWS_TOTAL = ROW_WO2 + 5 * NN; // 46080

__device__ __forceinline__ unsigned short f2bf(float f) {
  unsigned u = __float_as_uint(f);
  unsigned r = 0x7FFFu + ((u >> 16) & 1u);
  return (unsigned short)((u + r) >> 16);
}
__device__ __forceinline__ float bf2f(short s) {
  return __uint_as_float(((unsigned)(unsigned short)s) << 16);
}

// phi-domain encode of a pre-activation x (where t = tanh(x/2)):
//   value = sign(x) * phi(|x|),  phi(y) = log((1+e^-y)/(1-e^-y)) = -log(tanh(y/2))
//   x == 0  ->  +inf  (encodes t==0, excluded from products)
__device__ __forceinline__ unsigned short phi_enc(float x) {
  const float e = expf(-fabsf(x));
  const float phi = logf((1.f + e) / (1.f - e));  // +inf iff x==0
  return (unsigned short)(f2bf(phi) | (unsigned short)((__float_as_uint(x) >> 31) << 15));
}

__device__ __forceinline__ void gload16(const void* g, void* lds_base) {
  __builtin_amdgcn_global_load_lds(
      (const __attribute__((address_space(1))) void*)g,
      (__attribute__((address_space(3))) void*)lds_base, 16, 0, 0);
}

// ---- bf16 MFMA GEMM (m97-structure): C[M,Nd] = A[M,K] @ BT[Nd,K]^T (+add), f32 and/or bf16 out
__global__ __launch_bounds__(256, 2) void gemm_bt(
    const bf16* __restrict__ A, const bf16* __restrict__ BT,
    float* __restrict__ C, bf16* __restrict__ Cb, const float* __restrict__ add,
    int M, int Nd, int K)
{
  __shared__ bf16 As[128 * 32];
  __shared__ bf16 Bs[128 * 32];
  const int tid  = threadIdx.x;
  const int lane = tid & 63;
  const int w    = tid >> 6;
  const int bn = blockIdx.x, bm = blockIdx.y;
  const int wm = (w >> 1) * 64, wn = (w & 1) * 64;
  const int l15 = lane & 15;
  const int lk  = (lane >> 4) * 8;
  const int ld4 = (lane >> 4) * 4;
  const int sr  = lane >> 2;
  const int kc  = (lane & 3) * 8;

  f32x4 acc[4][4];
#pragma unroll
  for (int i = 0; i < 4; ++i)
#pragma unroll
    for (int j = 0; j < 4; ++j)
#pragma unroll
      for (int e = 0; e < 4; ++e) acc[i][j][e] = 0.f;

  const size_t rA = (size_t)bm * 128;
  const size_t rB = (size_t)bn * 128;

  for (int kt = 0; kt < K; kt += 32) {
#pragma unroll
    for (int c = 0; c < 2; ++c) {
      const int slot = w * 2 + c;
      const int r = slot * 16 + sr;
      gload16(A  + (rA + r) * (size_t)K + kt + kc, &As[slot * 512]);
      gload16(BT + (rB + r) * (size_t)K + kt + kc, &Bs[slot * 512]);
    }
    __syncthreads();
    short8 af[4], bfr[4];
#pragma unroll
    for (int f = 0; f < 4; ++f) {
      af[f]  = *(const short8*)&As[(wm + f * 16 + l15) * 32 + lk];
      bfr[f] = *(const short8*)&Bs[(wn + f * 16 + l15) * 32 + lk];
    }
#pragma unroll
    for (int i = 0; i < 4; ++i)
#pragma unroll
      for (int j = 0; j < 4; ++j)
        acc[i][j] = __builtin_amdgcn_mfma_f32_16x16x32_bf16(af[i], bfr[j], acc[i][j], 0, 0, 0);
    __syncthreads();
  }

#pragma unroll
  for (int i = 0; i < 4; ++i) {
    const int row0 = bm * 128 + wm + i * 16 + ld4;
#pragma unroll
    for (int j = 0; j < 4; ++j) {
      const int col = bn * 128 + wn + j * 16 + l15;
#pragma unroll
      for (int e = 0; e < 4; ++e) {
        const size_t o = (size_t)(row0 + e) * Nd + col;
        float v = acc[i][j][e];
        if (add) v += add[o];
        if (C)  C[o] = v;
        if (Cb) Cb[o] = __float2bfloat16(v);
      }
    }
  }
}

// ---- prep: SmIT[k][n][m] = bf16(S[k][m][n] - (m==n))
__global__ __launch_bounds__(256) void prep_smit(const float* __restrict__ S, bf16* __restrict__ out)
{
  __shared__ float ls[64][65];
  const int k = blockIdx.z;
  const int n0 = blockIdx.x * 64, m0 = blockIdx.y * 64;
  const float* Sk = S + (size_t)k * NN * NN;
  bf16* ok = out + (size_t)k * NN * NN;
  const int tc = threadIdx.x & 63, tr = threadIdx.x >> 6;
#pragma unroll
  for (int i = 0; i < 16; ++i) {
    const int r = tr + i * 4;
    ls[r][tc] = Sk[(size_t)(m0 + r) * NN + n0 + tc];
  }
  __syncthreads();
#pragma unroll
  for (int i = 0; i < 16; ++i) {
    const int r = tr + i * 4;
    float v = ls[tc][r] - ((m0 + tc) == (n0 + r) ? 1.f : 0.f);
    ok[(size_t)(n0 + r) * NN + m0 + tc] = __float2bfloat16(v);
  }
}

// ---- prep: out[h][n] = bf16(Bsrc[n][h]);  Bsrc is (NN, H)
__global__ __launch_bounds__(256) void prep_bt(const float* __restrict__ Bsrc, bf16* __restrict__ out, int H)
{
  __shared__ float ls[64][65];
  const int h0 = blockIdx.x * 64, n0 = blockIdx.y * 64;
  const int tc = threadIdx.x & 63, tr = threadIdx.x >> 6;
#pragma unroll
  for (int i = 0; i < 16; ++i) {
    const int r = tr + i * 4;
    ls[r][tc] = Bsrc[(size_t)(n0 + r) * H + h0 + tc];
  }
  __syncthreads();
#pragma unroll
  for (int i = 0; i < 16; ++i) {
    const int r = tr + i * 4;
    out[(size_t)(h0 + r) * NN + n0 + tc] = __float2bfloat16(ls[tc][r]);
  }
}

// ---- CSR build: one block per row, ordered compaction (deterministic)
//      packed entry: u32 = bf16(val)<<16 | col
__global__ __launch_bounds__(256) void csr_build(
    const float* __restrict__ W, int rowlen,
    unsigned* __restrict__ pack, int* __restrict__ nnz, int row_off)
{
  const int row = blockIdx.x;
  const float* wr = W + (size_t)row * rowlen;
  const size_t base = (size_t)(row_off + row) * CAP;
  __shared__ int wtot[4];
  __shared__ int cbase;
  if (threadIdx.x == 0) cbase = 0;
  __syncthreads();
  const int lane = threadIdx.x & 63, wv = threadIdx.x >> 6;
  for (int c0 = 0; c0 < rowlen; c0 += 256) {
    const int c = c0 + threadIdx.x;
    const float v = wr[c];
    const bool nz = (v != 0.f);
    const unsigned long long m = __ballot(nz);
    const int rank = __popcll(m & ((1ull << lane) - 1ull));
    if (lane == 0) wtot[wv] = __popcll(m);
    __syncthreads();
    int pre = cbase;
    for (int i = 0; i < wv; ++i) pre += wtot[i];
    if (nz) {
      const int p = pre + rank;
      if (p < CAP) pack[base + p] = ((unsigned)f2bf(v) << 16) | (unsigned)c;
    }
    __syncthreads();
    if (threadIdx.x == 0) cbase += wtot[0] + wtot[1] + wtot[2] + wtot[3];
    __syncthreads();
  }
  if (threadIdx.x == 0) nnz[row_off + row] = (cbase < CAP ? cbase : CAP);
}

// ---- cn via LDS slice: block owns 8 batch cols; src slice (SRC rows x 8 bf16) in LDS.
template<int SRC, int D>
__global__ __launch_bounds__(512, 1) void cn_lds(
    const unsigned short* __restrict__ src,  // (SRC, BATCH) bf16 phi-encoded
    const int* __restrict__ idx, int HOUT,
    unsigned short* __restrict__ out)        // (HOUT, BATCH) bf16 LLR
{
  __shared__ unsigned short sl[SRC * 8];
  const int b0 = blockIdx.x * BB;
  const int tid = threadIdx.x;
#pragma unroll
  for (int h = tid; h < SRC; h += 512)
    *(u32x4*)&sl[h * 8] = *(const u32x4*)(src + (size_t)h * BATCH + b0);
  __syncthreads();

  for (int h = tid; h < HOUT; h += 512) {
    const int* ir = idx + (size_t)h * D;
    int rows[D];
#pragma unroll
    for (int d = 0; d < D; ++d) rows[d] = ir[d];
    short8 v[D];
#pragma unroll
    for (int d = 0; d < D; ++d) v[d] = *(const short8*)&sl[rows[d] * 8];
    float s[8];
    unsigned sg[8];
    bool any[8];
#pragma unroll
    for (int e = 0; e < 8; ++e) { s[e] = 0.f; sg[e] = 0u; any[e] = false; }
#pragma unroll
    for (int d = 0; d < D; ++d) {
#pragma unroll
      for (int e = 0; e < 8; ++e) {
        const unsigned bits = (unsigned)(unsigned short)v[d][e];
        sg[e] ^= bits >> 15;
        const unsigned a = bits & 0x7FFFu;
        const bool nz = (a != 0x7F80u);   // +inf encodes t==0 (excluded)
        any[e] |= nz;
        s[e] += nz ? __uint_as_float(a << 16) : 0.f;
      }
    }
    short8 ov;
#pragma unroll
    for (int e = 0; e < 8; ++e) {
      const float y = fmaxf(s[e], 1.0000005e-6f);   // == clip(|u|, 0.999999)
      const float u = expf(-y);
      float r = logf((1.f + u) / (1.f - u));
      r = any[e] ? r : 0.f;
      ov[e] = (short)(f2bf(r) | (unsigned short)(sg[e] << 15));
    }
    *(short8*)(out + (size_t)h * BATCH + b0) = ov;
  }
}

// ---- sparse Wv via LDS slice: t2p[h,b0..7] = phi_enc( z[h,b] + sum val*t1_lds[col][b] )
template<int H>
__global__ __launch_bounds__(512, 1) void sparse_wv_lds(
    const unsigned short* __restrict__ zb,   // (H, BATCH) bf16
    const unsigned short* __restrict__ t1,   // (H, BATCH) bf16 LLR
    const unsigned* __restrict__ pack, const int* __restrict__ nnz,
    int rowoff, unsigned short* __restrict__ t2p)
{
  __shared__ unsigned short sl[H * 8];
  const int b0 = blockIdx.x * BB;
  const int tid = threadIdx.x;
#pragma unroll
  for (int h = tid; h < H; h += 512)
    *(u32x4*)&sl[h * 8] = *(const u32x4*)(t1 + (size_t)h * BATCH + b0);
  __syncthreads();

  for (int h = tid; h < H; h += 512) {
    const int rg = rowoff + h;
    const unsigned* pr = pack + (size_t)rg * CAP;
    const int n = nnz[rg];
    const short8 z = *(const short8*)(zb + (size_t)h * BATCH + b0);
    f32x4 a0, a1;
#pragma unroll
    for (int e = 0; e < 4; ++e) { a0[e] = bf2f(z[e]); a1[e] = bf2f(z[e + 4]); }
    int j = 0;
    for (; j + 4 <= n; j += 4) {
      const u32x4 w4 = *(const u32x4*)(pr + j);
      short8 t[4];
#pragma unroll
      for (int q = 0; q < 4; ++q)
        t[q] = *(const short8*)&sl[(w4[q] & 0xFFFFu) * 8];
#pragma unroll
      for (int q = 0; q < 4; ++q) {
        const float v = bf2f((short)(w4[q] >> 16));
#pragma unroll
        for (int e = 0; e < 4; ++e) {
          a0[e] += v * bf2f(t[q][e]);
          a1[e] += v * bf2f(t[q][e + 4]);
        }
      }
    }
    for (; j < n; ++j) {
      const unsigned pk = pr[j];
      const float v = bf2f((short)(pk >> 16));
      const short8 t = *(const short8*)&sl[(pk & 0xFFFFu) * 8];
#pragma unroll
      for (int e = 0; e < 4; ++e) {
        a0[e] += v * bf2f(t[e]);
        a1[e] += v * bf2f(t[e + 4]);
      }
    }
    short8 ov;
#pragma unroll
    for (int e = 0; e < 4; ++e) {
      ov[e]     = (short)phi_enc(a0[e]);   // t2 = tanh(0.5*a) -> phi domain
      ov[e + 4] = (short)phi_enc(a1[e]);
    }
    *(short8*)(t2p + (size_t)h * BATCH + b0) = ov;
  }
}

// ---- sparse Wout via LDS slice: xp[n,b0..7] = sum val*t3_lds[col][b]
template<int H>
__global__ __launch_bounds__(512, 1) void sparse_wo_lds(
    const unsigned short* __restrict__ t3,   // (H, BATCH) bf16 LLR
    const unsigned* __restrict__ pack, const int* __restrict__ nnz,
    int rowoff, float* __restrict__ xp)      // (NN, BATCH) f32
{
  __shared__ unsigned short sl[H * 8];
  const int b0 = blockIdx.x * BB;
  const int tid = threadIdx.x;
#pragma unroll
  for (int h = tid; h < H; h += 512)
    *(u32x4*)&sl[h * 8] = *(const u32x4*)(t3 + (size_t)h * BATCH + b0);
  __syncthreads();

  for (int nr = tid; nr < NN; nr += 512) {
    const int rg = rowoff + nr;
    const unsigned* pr = pack + (size_t)rg * CAP;
    const int cnt = nnz[rg];
    f32x4 a0 = {0.f, 0.f, 0.f, 0.f};
    f32x4 a1 = {0.f, 0.f, 0.f, 0.f};
    int j = 0;
    for (; j + 4 <= cnt; j += 4) {
      const u32x4 w4 = *(const u32x4*)(pr + j);
      short8 t[4];
#pragma unroll
      for (int q = 0; q < 4; ++q)
        t[q] = *(const short8*)&sl[(w4[q] & 0xFFFFu) * 8];
#pragma unroll
      for (int q = 0; q < 4; ++q) {
        const float v = bf2f((short)(w4[q] >> 16));
#pragma unroll
        for (int e = 0; e < 4; ++e) {
          a0[e] += v * bf2f(t[q][e]);
          a1[e] += v * bf2f(t[q][e + 4]);
        }
      }
    }
    for (; j < cnt; ++j) {
      const unsigned pk = pr[j];
      const float v = bf2f((short)(pk >> 16));
      const short8 t = *(const short8*)&sl[(pk & 0xFFFFu) * 8];
#pragma unroll
      for (int e = 0; e < 4; ++e) {
        a0[e] += v * bf2f(t[e]);
        a1[e] += v * bf2f(t[e + 4]);
      }
    }
    float* orow = xp + (size_t)nr * BATCH + b0;
    *(f32x4*)orow = a0;
    *(f32x4*)(orow + 4) = a1;
  }
}

// ---- fused epilogue: x_new = chS + xp^T; sigmoid->out, x f32, x bf16 (B,N), phi(x)->tfT (N,B)
__global__ __launch_bounds__(256) void fuse_out(
    const float* __restrict__ xpT,
    const float* __restrict__ chS,
    float* __restrict__ dout,
    float* __restrict__ xf,
    bf16* __restrict__ xb,
    unsigned short* __restrict__ tfT)
{
  __shared__ float lc[64][65];
  __shared__ float lx[64][65];
  const int n0 = blockIdx.x * 64, b0 = blockIdx.y * 64;
  const int tc = threadIdx.x & 63, tr = threadIdx.x >> 6;
#pragma unroll
  for (int i = 0; i < 16; ++i) {
    const int r = tr + i * 4;
    lc[r][tc] = chS[(size_t)(b0 + r) * NN + n0 + tc];
    lx[r][tc] = xpT[(size_t)(n0 + r) * BATCH + b0 + tc];
  }
  __syncthreads();
#pragma unroll
  for (int i = 0; i < 16; ++i) {
    const int r = tr + i * 4;
    const float v = lc[r][tc] + lx[tc][r];
    const size_t o = (size_t)(b0 + r) * NN + n0 + tc;
    dout[o] = 1.f / (1.f + expf(-v));
    xf[o] = v;
    xb[o] = __float2bfloat16(v);
  }
#pragma unroll
  for (int i = 0; i < 16; ++i) {
    const int r = tr + i * 4;
    const float v = lc[tc][r] + lx[r][tc];
    tfT[(size_t)(n0 + r) * BATCH + b0 + tc] = phi_enc(v);
  }
}

// ---- initial prep (k=0): from x (B,N) make xb (B,N) and phi(x)->tfT (N,B)
__global__ __launch_bounds__(256) void init_prep(
    const float* __restrict__ x, bf16* __restrict__ xb, unsigned short* __restrict__ tfT)
{
  __shared__ float ls[64][65];
  const int n0 = blockIdx.x * 64, b0 = blockIdx.y * 64;
  const int tc = threadIdx.x & 63, tr = threadIdx.x >> 6;
#pragma unroll
  for (int i = 0; i < 16; ++i) {
    const int r = tr + i * 4;
    const size_t o = (size_t)(b0 + r) * NN + n0 + tc;
    const float v = x[o];
    ls[r][tc] = v;
    xb[o] = __float2bfloat16(v);
  }
  __syncthreads();
#pragma unroll
  for (int i = 0; i < 16; ++i) {
    const int r = tr + i * 4;
    tfT[(size_t)(n0 + r) * BATCH + b0 + tc] = phi_enc(ls[tc][r]);
  }
}

extern "C" void kernel_launch(void* const* d_in, const int* in_sizes, int n_in,
                              void* d_out, int out_size, void* d_ws, size_t ws_size,
                              hipStream_t stream)
{
  const float* x_in  = (const float*)d_in[0];
  const float* S     = (const float*)d_in[1];
  const float* B1    = (const float*)d_in[2];
  const float* B2    = (const float*)d_in[3];
  const float* Wv1   = (const float*)d_in[4];
  const float* Wout1 = (const float*)d_in[5];
  const float* Wv2   = (const float*)d_in[6];
  const float* Wout2 = (const float*)d_in[7];
  const int* idx1f   = (const int*)d_in[8];
  const int* idx1m   = (const int*)d_in[9];
  const int* idx2f   = (const int*)d_in[10];
  const int* idx2m   = (const int*)d_in[11];
  float* out = (float*)d_out;

  uint8_t* p = (uint8_t*)d_ws;
  auto alloc = [&](size_t bytes) -> void* {
    void* r = p;
    p += (bytes + 255) & ~(size_t)255;
    return r;
  };
  bf16*  SmIT = (bf16*)alloc((size_t)10 * NN * NN * sizeof(bf16));
  bf16*  B1T  = (bf16*)alloc((size_t)H1C * NN * sizeof(bf16));
  bf16*  B2T  = (bf16*)alloc((size_t)H2C * NN * sizeof(bf16));
  unsigned* cpack = (unsigned*)alloc((size_t)ROWS_TOTAL * CAP * sizeof(unsigned));
  int*   cnnz  = (int*)alloc((size_t)ROWS_TOTAL * sizeof(int));
  float* xf   = (float*)alloc((size_t)BATCH * NN * sizeof(float));
  bf16*  xb   = (bf16*)alloc((size_t)BATCH * NN * sizeof(bf16));
  unsigned short* tfT = (unsigned short*)alloc((size_t)NN * BATCH * sizeof(unsigned short)); // phi(x)
  float* chS  = (float*)alloc((size_t)BATCH * NN * sizeof(float));
  bf16*  chSb = (bf16*)alloc((size_t)BATCH * NN * sizeof(bf16));
  unsigned short* t1T = (unsigned short*)alloc((size_t)H2C * BATCH * sizeof(unsigned short)); // bf16 LLR t1/t3
  unsigned short* zTb = (unsigned short*)alloc((size_t)H2C * BATCH * sizeof(unsigned short)); // bf16 z
  unsigned short* t2p = (unsigned short*)alloc((size_t)H2C * BATCH * sizeof(unsigned short)); // phi(t2)
  float* xpT  = (float*)alloc((size_t)NN * BATCH * sizeof(float));
  (void)ws_size; (void)in_sizes; (void)n_in; (void)out_size;

  // --- per-call prep
  prep_smit<<<dim3(NN / 64, NN / 64, 10), 256, 0, stream>>>(S, SmIT);
  prep_bt<<<dim3(H1C / 64, NN / 64), 256, 0, stream>>>(B1, B1T, H1C);
  prep_bt<<<dim3(H2C / 64, NN / 64), 256, 0, stream>>>(B2, B2T, H2C);
  csr_build<<<5 * H1C, 256, 0, stream>>>(Wv1,   H1C, cpack, cnnz, ROW_WV1);
  csr_build<<<5 * NN,  256, 0, stream>>>(Wout1, H1C, cpack, cnnz, ROW_WO1);
  csr_build<<<5 * H2C, 256, 0, stream>>>(Wv2,   H2C, cpack, cnnz, ROW_WV2);
  csr_build<<<5 * NN,  256, 0, stream>>>(Wout2, H2C, cpack, cnnz, ROW_WO2);
  init_prep<<<dim3(NN / 64, BATCH / 64), 256, 0, stream>>>(x_in, xb, tfT);

  for (int k = 0; k < 10; ++k) {
    const bool g1 = (k % 2 == 0);
    const int j = k / 2;
    const int H = g1 ? H1C : H2C;
    const bf16* BmT = g1 ? B1T : B2T;
    const int* idf = g1 ? idx1f : idx2f;
    const int* idm = g1 ? idx1m : idx2m;
    const int wv_off = g1 ? (ROW_WV1 + j * H1C) : (ROW_WV2 + j * H2C);
    const int wo_off = g1 ? (ROW_WO1 + j * NN)  : (ROW_WO2 + j * NN);
    const float* xcur = (k == 0) ? x_in : xf;

    // chS = x + x @ (S[k]-I)
    gemm_bt<<<dim3(NN / 128, BATCH / 128), 256, 0, stream>>>(
        xb, SmIT + (size_t)k * NN * NN, chS, chSb, xcur, BATCH, NN, NN);
    // t1T = bf16 LLR of cn over phi-encoded tfT (src NN rows)
    if (g1) cn_lds<NN, 6><<<NBLK, 512, 0, stream>>>(tfT, idf, H1C, t1T);
    else    cn_lds<NN, 8><<<NBLK, 512, 0, stream>>>(tfT, idf, H2C, t1T);
    // zTb = bf16( BmT @ chS^T )
    gemm_bt<<<dim3(BATCH / 128, H / 128), 256, 0, stream>>>(
        BmT, chSb, nullptr, (bf16*)zTb, nullptr, H, BATCH, NN);
    // t2p = phi( z + Wv @ t1 )
    if (g1) sparse_wv_lds<H1C><<<NBLK, 512, 0, stream>>>(zTb, t1T, cpack, cnnz, wv_off, t2p);
    else    sparse_wv_lds<H2C><<<NBLK, 512, 0, stream>>>(zTb, t1T, cpack, cnnz, wv_off, t2p);
    // t3T = bf16 LLR of cn over phi-encoded t2p  -> t1T
    if (g1) cn_lds<H1C, 6><<<NBLK, 512, 0, stream>>>(t2p, idm, H1C, t1T);
    else    cn_lds<H2C, 8><<<NBLK, 512, 0, stream>>>(t2p, idm, H2C, t1T);
    // xpT = Wout @ t3
    if (g1) sparse_wo_lds<H1C><<<NBLK, 512, 0, stream>>>(t1T, cpack, cnnz, wo_off, xpT);
    else    sparse_wo_lds<H2C><<<NBLK, 512, 0, stream>>>(t1T, cpack, cnnz, wo_off, xpT);
    // epilogue
    fuse_out<<<dim3(NN / 64, BATCH / 64), 256, 0, stream>>>(
        xpT, chS, out + (size_t)k * BATCH * NN, xf, xb, tfT);
  }
}

// Round 10
// 1997.143 us; speedup vs baseline: 1.4877x; 1.4877x over previous
//
#include <hip/hip_runtime.h>
#include <hip/hip_bf16.h>
#include <stdint.h>
#include <stddef.h>

using bf16 = __hip_bfloat16;
typedef __attribute__((ext_vector_type(8))) short short8;
typedef __attribute__((ext_vector_type(2))) float f32x2;
typedef __attribute__((ext_vector_type(4))) float f32x4;
typedef __attribute__((ext_vector_type(4))) unsigned u32x4;

constexpr int BATCH = 2048;
constexpr int NN    = 1024;
constexpr int H1C   = 3072;
constexpr int H2C   = 4096;
constexpr int CAP   = 128;   // max nnz per sparse row

// CSR global row offsets
constexpr int ROW_WV1 = 0;                 // 5*3072 rows, len 3072
constexpr int ROW_WO1 = 5 * H1C;           // 5*1024 rows, len 3072
constexpr int ROW_WV2 = ROW_WO1 + 5 * NN;  // 5*4096 rows, len 4096
constexpr int ROW_WO2 = ROW_WV2 + 5 * H2C; // 5*1024 rows, len 4096
constexpr int ROWS_TOTAL = ROW_WO2 + 5 * NN; // 46080

__device__ __forceinline__ unsigned short f2bf(float f) {
  unsigned u = __float_as_uint(f);
  unsigned r = 0x7FFFu + ((u >> 16) & 1u);
  return (unsigned short)((u + r) >> 16);
}
__device__ __forceinline__ float bf2f(short s) {
  return __uint_as_float(((unsigned)(unsigned short)s) << 16);
}

// phi-domain encode of a pre-activation x (where t = tanh(x/2)):
//   value = sign(x) * phi(|x|),  phi(y) = log((1+e^-y)/(1-e^-y)) = -log(tanh(y/2))
//   x == 0  ->  +inf  (encodes t==0, excluded from products)
__device__ __forceinline__ unsigned short phi_enc(float x) {
  const float e = expf(-fabsf(x));
  const float phi = logf((1.f + e) / (1.f - e));  // +inf iff x==0
  return (unsigned short)(f2bf(phi) | (unsigned short)((__float_as_uint(x) >> 31) << 15));
}

__device__ __forceinline__ void gload16(const void* g, void* lds_base) {
  __builtin_amdgcn_global_load_lds(
      (const __attribute__((address_space(1))) void*)g,
      (__attribute__((address_space(3))) void*)lds_base, 16, 0, 0);
}

// ---- bf16 MFMA GEMM (m97-structure): C[M,Nd] = A[M,K] @ BT[Nd,K]^T (+add), f32 and/or bf16 out
__global__ __launch_bounds__(256, 2) void gemm_bt(
    const bf16* __restrict__ A, const bf16* __restrict__ BT,
    float* __restrict__ C, bf16* __restrict__ Cb, const float* __restrict__ add,
    int M, int Nd, int K)
{
  __shared__ bf16 As[128 * 32];
  __shared__ bf16 Bs[128 * 32];
  const int tid  = threadIdx.x;
  const int lane = tid & 63;
  const int w    = tid >> 6;
  const int bn = blockIdx.x, bm = blockIdx.y;
  const int wm = (w >> 1) * 64, wn = (w & 1) * 64;
  const int l15 = lane & 15;
  const int lk  = (lane >> 4) * 8;
  const int ld4 = (lane >> 4) * 4;
  const int sr  = lane >> 2;
  const int kc  = (lane & 3) * 8;

  f32x4 acc[4][4];
#pragma unroll
  for (int i = 0; i < 4; ++i)
#pragma unroll
    for (int j = 0; j < 4; ++j)
#pragma unroll
      for (int e = 0; e < 4; ++e) acc[i][j][e] = 0.f;

  const size_t rA = (size_t)bm * 128;
  const size_t rB = (size_t)bn * 128;

  for (int kt = 0; kt < K; kt += 32) {
#pragma unroll
    for (int c = 0; c < 2; ++c) {
      const int slot = w * 2 + c;
      const int r = slot * 16 + sr;
      gload16(A  + (rA + r) * (size_t)K + kt + kc, &As[slot * 512]);
      gload16(BT + (rB + r) * (size_t)K + kt + kc, &Bs[slot * 512]);
    }
    __syncthreads();
    short8 af[4], bfr[4];
#pragma unroll
    for (int f = 0; f < 4; ++f) {
      af[f]  = *(const short8*)&As[(wm + f * 16 + l15) * 32 + lk];
      bfr[f] = *(const short8*)&Bs[(wn + f * 16 + l15) * 32 + lk];
    }
#pragma unroll
    for (int i = 0; i < 4; ++i)
#pragma unroll
      for (int j = 0; j < 4; ++j)
        acc[i][j] = __builtin_amdgcn_mfma_f32_16x16x32_bf16(af[i], bfr[j], acc[i][j], 0, 0, 0);
    __syncthreads();
  }

#pragma unroll
  for (int i = 0; i < 4; ++i) {
    const int row0 = bm * 128 + wm + i * 16 + ld4;
#pragma unroll
    for (int j = 0; j < 4; ++j) {
      const int col = bn * 128 + wn + j * 16 + l15;
#pragma unroll
      for (int e = 0; e < 4; ++e) {
        const size_t o = (size_t)(row0 + e) * Nd + col;
        float v = acc[i][j][e];
        if (add) v += add[o];
        if (C)  C[o] = v;
        if (Cb) Cb[o] = __float2bfloat16(v);
      }
    }
  }
}

// ---- prep: SmIT[k][n][m] = bf16(S[k][m][n] - (m==n))
__global__ __launch_bounds__(256) void prep_smit(const float* __restrict__ S, bf16* __restrict__ out)
{
  __shared__ float ls[64][65];
  const int k = blockIdx.z;
  const int n0 = blockIdx.x * 64, m0 = blockIdx.y * 64;
  const float* Sk = S + (size_t)k * NN * NN;
  bf16* ok = out + (size_t)k * NN * NN;
  const int tc = threadIdx.x & 63, tr = threadIdx.x >> 6;
#pragma unroll
  for (int i = 0; i < 16; ++i) {
    const int r = tr + i * 4;
    ls[r][tc] = Sk[(size_t)(m0 + r) * NN + n0 + tc];
  }
  __syncthreads();
#pragma unroll
  for (int i = 0; i < 16; ++i) {
    const int r = tr + i * 4;
    float v = ls[tc][r] - ((m0 + tc) == (n0 + r) ? 1.f : 0.f);
    ok[(size_t)(n0 + r) * NN + m0 + tc] = __float2bfloat16(v);
  }
}

// ---- prep: out[h][n] = bf16(Bsrc[n][h]);  Bsrc is (NN, H)
__global__ __launch_bounds__(256) void prep_bt(const float* __restrict__ Bsrc, bf16* __restrict__ out, int H)
{
  __shared__ float ls[64][65];
  const int h0 = blockIdx.x * 64, n0 = blockIdx.y * 64;
  const int tc = threadIdx.x & 63, tr = threadIdx.x >> 6;
#pragma unroll
  for (int i = 0; i < 16; ++i) {
    const int r = tr + i * 4;
    ls[r][tc] = Bsrc[(size_t)(n0 + r) * H + h0 + tc];
  }
  __syncthreads();
#pragma unroll
  for (int i = 0; i < 16; ++i) {
    const int r = tr + i * 4;
    out[(size_t)(h0 + r) * NN + n0 + tc] = __float2bfloat16(ls[tc][r]);
  }
}

// ---- CSR build: one block per row, ordered compaction (deterministic)
//      packed entry: u32 = bf16(val)<<16 | col
__global__ __launch_bounds__(256) void csr_build(
    const float* __restrict__ W, int rowlen,
    unsigned* __restrict__ pack, int* __restrict__ nnz, int row_off)
{
  const int row = blockIdx.x;
  const float* wr = W + (size_t)row * rowlen;
  const size_t base = (size_t)(row_off + row) * CAP;
  __shared__ int wtot[4];
  __shared__ int cbase;
  if (threadIdx.x == 0) cbase = 0;
  __syncthreads();
  const int lane = threadIdx.x & 63, wv = threadIdx.x >> 6;
  for (int c0 = 0; c0 < rowlen; c0 += 256) {
    const int c = c0 + threadIdx.x;
    const float v = wr[c];
    const bool nz = (v != 0.f);
    const unsigned long long m = __ballot(nz);
    const int rank = __popcll(m & ((1ull << lane) - 1ull));
    if (lane == 0) wtot[wv] = __popcll(m);
    __syncthreads();
    int pre = cbase;
    for (int i = 0; i < wv; ++i) pre += wtot[i];
    if (nz) {
      const int p = pre + rank;
      if (p < CAP) pack[base + p] = ((unsigned)f2bf(v) << 16) | (unsigned)c;
    }
    __syncthreads();
    if (threadIdx.x == 0) cbase += wtot[0] + wtot[1] + wtot[2] + wtot[3];
    __syncthreads();
  }
  if (threadIdx.x == 0) nnz[row_off + row] = (cbase < CAP ? cbase : CAP);
}

// ---- cn_update + clip + 2*atanh, phi-domain source (bf16), compile-time D.
//      FP8OUT: write LLR as fp8 e4m3 (1B/elem) for the wv gather; else bf16.
template<int D, bool FP8OUT>
__global__ __launch_bounds__(256) void cn_kernel(
    const unsigned short* __restrict__ src,  // (rows, BATCH) bf16 phi-encoded
    const int* __restrict__ idx,
    void* __restrict__ out)                  // (H, BATCH) fp8 or bf16 LLR
{
  const int h = blockIdx.x;
  const int b = threadIdx.x * 8;
  const int* ir = idx + (size_t)h * D;
  int rows[D];
#pragma unroll
  for (int d = 0; d < D; ++d) rows[d] = ir[d];
  short8 v[D];
#pragma unroll
  for (int d = 0; d < D; ++d)
    v[d] = *(const short8*)(src + (size_t)rows[d] * BATCH + b);
  float s[8];
  unsigned sg[8];
  bool any[8];
#pragma unroll
  for (int e = 0; e < 8; ++e) { s[e] = 0.f; sg[e] = 0u; any[e] = false; }
#pragma unroll
  for (int d = 0; d < D; ++d) {
#pragma unroll
    for (int e = 0; e < 8; ++e) {
      const unsigned bits = (unsigned)(unsigned short)v[d][e];
      sg[e] ^= bits >> 15;
      const unsigned a = bits & 0x7FFFu;
      const bool nz = (a != 0x7F80u);   // +inf encodes t==0 (excluded)
      any[e] |= nz;
      s[e] += nz ? __uint_as_float(a << 16) : 0.f;
    }
  }
  float rs[8];
#pragma unroll
  for (int e = 0; e < 8; ++e) {
    const float y = fmaxf(s[e], 1.0000005e-6f);   // == clip(|u|, 0.999999)
    const float u = expf(-y);
    float r = logf((1.f + u) / (1.f - u));
    r = any[e] ? r : 0.f;
    rs[e] = __uint_as_float(__float_as_uint(r) | (sg[e] << 31));
  }
  if constexpr (FP8OUT) {
    int lo = 0, hi = 0;
    lo = __builtin_amdgcn_cvt_pk_fp8_f32(rs[0], rs[1], lo, false);
    lo = __builtin_amdgcn_cvt_pk_fp8_f32(rs[2], rs[3], lo, true);
    hi = __builtin_amdgcn_cvt_pk_fp8_f32(rs[4], rs[5], hi, false);
    hi = __builtin_amdgcn_cvt_pk_fp8_f32(rs[6], rs[7], hi, true);
    int2 o; o.x = lo; o.y = hi;
    *(int2*)((uint8_t*)out + (size_t)h * BATCH + b) = o;
  } else {
    short8 ov;
#pragma unroll
    for (int e = 0; e < 8; ++e) {
      const unsigned ub = __float_as_uint(rs[e]);
      ov[e] = (short)(f2bf(__uint_as_float(ub & 0x7FFFFFFFu)) | (unsigned short)((ub >> 31) << 15));
    }
    *(short8*)((unsigned short*)out + (size_t)h * BATCH + b) = ov;
  }
}

// ---- sparse Wv apply: t2p[h,b] = phi_enc( z[h,b] + sum val*t1[col,b] ), t1 is fp8 e4m3
__global__ __launch_bounds__(256) void sparse_wv(
    const unsigned short* __restrict__ zb, const uint8_t* __restrict__ t1f8,
    const unsigned* __restrict__ pack, const int* __restrict__ nnz,
    int rowoff, unsigned short* __restrict__ t2p)
{
  const int h = blockIdx.x;
  const int b = threadIdx.x * 8;
  const int rg = rowoff + h;
  const unsigned* pr = pack + (size_t)rg * CAP;
  const int n = nnz[rg];
  const short8 z = *(const short8*)(zb + (size_t)h * BATCH + b);
  f32x4 a0, a1;
#pragma unroll
  for (int e = 0; e < 4; ++e) { a0[e] = bf2f(z[e]); a1[e] = bf2f(z[e + 4]); }
  int j = 0;
  for (; j + 4 <= n; j += 4) {
    const u32x4 w4 = *(const u32x4*)(pr + j);
    int2 t[4];
#pragma unroll
    for (int q = 0; q < 4; ++q)
      t[q] = *(const int2*)(t1f8 + (size_t)(w4[q] & 0xFFFFu) * BATCH + b);
#pragma unroll
    for (int q = 0; q < 4; ++q) {
      const float v = bf2f((short)(w4[q] >> 16));
      const f32x2 p01 = __builtin_amdgcn_cvt_pk_f32_fp8(t[q].x, false);
      const f32x2 p23 = __builtin_amdgcn_cvt_pk_f32_fp8(t[q].x, true);
      const f32x2 p45 = __builtin_amdgcn_cvt_pk_f32_fp8(t[q].y, false);
      const f32x2 p67 = __builtin_amdgcn_cvt_pk_f32_fp8(t[q].y, true);
      a0[0] += v * p01[0]; a0[1] += v * p01[1];
      a0[2] += v * p23[0]; a0[3] += v * p23[1];
      a1[0] += v * p45[0]; a1[1] += v * p45[1];
      a1[2] += v * p67[0]; a1[3] += v * p67[1];
    }
  }
  for (; j < n; ++j) {
    const unsigned pk = pr[j];
    const float v = bf2f((short)(pk >> 16));
    const int2 t = *(const int2*)(t1f8 + (size_t)(pk & 0xFFFFu) * BATCH + b);
    const f32x2 p01 = __builtin_amdgcn_cvt_pk_f32_fp8(t.x, false);
    const f32x2 p23 = __builtin_amdgcn_cvt_pk_f32_fp8(t.x, true);
    const f32x2 p45 = __builtin_amdgcn_cvt_pk_f32_fp8(t.y, false);
    const f32x2 p67 = __builtin_amdgcn_cvt_pk_f32_fp8(t.y, true);
    a0[0] += v * p01[0]; a0[1] += v * p01[1];
    a0[2] += v * p23[0]; a0[3] += v * p23[1];
    a1[0] += v * p45[0]; a1[1] += v * p45[1];
    a1[2] += v * p67[0]; a1[3] += v * p67[1];
  }
  short8 ov;
#pragma unroll
  for (int e = 0; e < 4; ++e) {
    ov[e]     = (short)phi_enc(a0[e]);   // t2 = tanh(0.5*a) -> phi domain
    ov[e + 4] = (short)phi_enc(a1[e]);
  }
  *(short8*)(t2p + (size_t)h * BATCH + b) = ov;
}

// ---- sparse Wout apply: xp[n,b] = sum val*t3[col,b], t3 bf16, unroll-4 j-loop
__global__ __launch_bounds__(256) void sparse_wo(
    const unsigned short* __restrict__ t3,
    const unsigned* __restrict__ pack, const int* __restrict__ nnz,
    int rowoff, float* __restrict__ xp)
{
  const int nrow = blockIdx.x;
  const int b = threadIdx.x * 8;
  const int rg = rowoff + nrow;
  const unsigned* pr = pack + (size_t)rg * CAP;
  const int cnt = nnz[rg];
  f32x4 a0 = {0.f, 0.f, 0.f, 0.f};
  f32x4 a1 = {0.f, 0.f, 0.f, 0.f};
  int j = 0;
  for (; j + 4 <= cnt; j += 4) {
    const u32x4 w4 = *(const u32x4*)(pr + j);
    short8 t[4];
#pragma unroll
    for (int q = 0; q < 4; ++q)
      t[q] = *(const short8*)(t3 + (size_t)(w4[q] & 0xFFFFu) * BATCH + b);
#pragma unroll
    for (int q = 0; q < 4; ++q) {
      const float v = bf2f((short)(w4[q] >> 16));
#pragma unroll
      for (int e = 0; e < 4; ++e) {
        a0[e] += v * bf2f(t[q][e]);
        a1[e] += v * bf2f(t[q][e + 4]);
      }
    }
  }
  for (; j < cnt; ++j) {
    const unsigned pk = pr[j];
    const float v = bf2f((short)(pk >> 16));
    const short8 t = *(const short8*)(t3 + (size_t)(pk & 0xFFFFu) * BATCH + b);
#pragma unroll
    for (int e = 0; e < 4; ++e) {
      a0[e] += v * bf2f(t[e]);
      a1[e] += v * bf2f(t[e + 4]);
    }
  }
  float* orow = xp + (size_t)nrow * BATCH + b;
  *(f32x4*)orow = a0;
  *(f32x4*)(orow + 4) = a1;
}

// ---- fused epilogue: x_new = chS + xp^T; sigmoid->out, x f32, x bf16 (B,N), phi(x)->tfT (N,B)
__global__ __launch_bounds__(256) void fuse_out(
    const float* __restrict__ xpT,
    const float* __restrict__ chS,
    float* __restrict__ dout,
    float* __restrict__ xf,
    bf16* __restrict__ xb,
    unsigned short* __restrict__ tfT)
{
  __shared__ float lc[64][65];
  __shared__ float lx[64][65];
  const int n0 = blockIdx.x * 64, b0 = blockIdx.y * 64;
  const int tc = threadIdx.x & 63, tr = threadIdx.x >> 6;
#pragma unroll
  for (int i = 0; i < 16; ++i) {
    const int r = tr + i * 4;
    lc[r][tc] = chS[(size_t)(b0 + r) * NN + n0 + tc];
    lx[r][tc] = xpT[(size_t)(n0 + r) * BATCH + b0 + tc];
  }
  __syncthreads();
#pragma unroll
  for (int i = 0; i < 16; ++i) {
    const int r = tr + i * 4;
    const float v = lc[r][tc] + lx[tc][r];
    const size_t o = (size_t)(b0 + r) * NN + n0 + tc;
    dout[o] = 1.f / (1.f + expf(-v));
    xf[o] = v;
    xb[o] = __float2bfloat16(v);
  }
#pragma unroll
  for (int i = 0; i < 16; ++i) {
    const int r = tr + i * 4;
    const float v = lc[tc][r] + lx[r][tc];
    tfT[(size_t)(n0 + r) * BATCH + b0 + tc] = phi_enc(v);
  }
}

// ---- initial prep (k=0): from x (B,N) make xb (B,N) and phi(x)->tfT (N,B)
__global__ __launch_bounds__(256) void init_prep(
    const float* __restrict__ x, bf16* __restrict__ xb, unsigned short* __restrict__ tfT)
{
  __shared__ float ls[64][65];
  const int n0 = blockIdx.x * 64, b0 = blockIdx.y * 64;
  const int tc = threadIdx.x & 63, tr = threadIdx.x >> 6;
#pragma unroll
  for (int i = 0; i < 16; ++i) {
    const int r = tr + i * 4;
    const size_t o = (size_t)(b0 + r) * NN + n0 + tc;
    const float v = x[o];
    ls[r][tc] = v;
    xb[o] = __float2bfloat16(v);
  }
  __syncthreads();
#pragma unroll
  for (int i = 0; i < 16; ++i) {
    const int r = tr + i * 4;
    tfT[(size_t)(n0 + r) * BATCH + b0 + tc] = phi_enc(ls[tc][r]);
  }
}

extern "C" void kernel_launch(void* const* d_in, const int* in_sizes, int n_in,
                              void* d_out, int out_size, void* d_ws, size_t ws_size,
                              hipStream_t stream)
{
  const float* x_in  = (const float*)d_in[0];
  const float* S     = (const float*)d_in[1];
  const float* B1    = (const float*)d_in[2];
  const float* B2    = (const float*)d_in[3];
  const float* Wv1   = (const float*)d_in[4];
  const float* Wout1 = (const float*)d_in[5];
  const float* Wv2   = (const float*)d_in[6];
  const float* Wout2 = (const float*)d_in[7];
  const int* idx1f   = (const int*)d_in[8];
  const int* idx1m   = (const int*)d_in[9];
  const int* idx2f   = (const int*)d_in[10];
  const int* idx2m   = (const int*)d_in[11];
  float* out = (float*)d_out;

  uint8_t* p = (uint8_t*)d_ws;
  auto alloc = [&](size_t bytes) -> void* {
    void* r = p;
    p += (bytes + 255) & ~(size_t)255;
    return r;
  };
  bf16*  SmIT = (bf16*)alloc((size_t)10 * NN * NN * sizeof(bf16));
  bf16*  B1T  = (bf16*)alloc((size_t)H1C * NN * sizeof(bf16));
  bf16*  B2T  = (bf16*)alloc((size_t)H2C * NN * sizeof(bf16));
  unsigned* cpack = (unsigned*)alloc((size_t)ROWS_TOTAL * CAP * sizeof(unsigned));
  int*   cnnz  = (int*)alloc((size_t)ROWS_TOTAL * sizeof(int));
  float* xf   = (float*)alloc((size_t)BATCH * NN * sizeof(float));
  bf16*  xb   = (bf16*)alloc((size_t)BATCH * NN * sizeof(bf16));
  unsigned short* tfT = (unsigned short*)alloc((size_t)NN * BATCH * sizeof(unsigned short)); // phi(x)
  float* chS  = (float*)alloc((size_t)BATCH * NN * sizeof(float));
  bf16*  chSb = (bf16*)alloc((size_t)BATCH * NN * sizeof(bf16));
  uint8_t* t1f8 = (uint8_t*)alloc((size_t)H2C * BATCH);                                       // fp8 t1
  unsigned short* t3T = (unsigned short*)alloc((size_t)H2C * BATCH * sizeof(unsigned short)); // bf16 t3
  unsigned short* zTb = (unsigned short*)alloc((size_t)H2C * BATCH * sizeof(unsigned short)); // bf16 z
  unsigned short* t2p = (unsigned short*)alloc((size_t)H2C * BATCH * sizeof(unsigned short)); // phi(t2)
  float* xpT  = (float*)alloc((size_t)NN * BATCH * sizeof(float));
  (void)ws_size; (void)in_sizes; (void)n_in; (void)out_size;

  // --- per-call prep
  prep_smit<<<dim3(NN / 64, NN / 64, 10), 256, 0, stream>>>(S, SmIT);
  prep_bt<<<dim3(H1C / 64, NN / 64), 256, 0, stream>>>(B1, B1T, H1C);
  prep_bt<<<dim3(H2C / 64, NN / 64), 256, 0, stream>>>(B2, B2T, H2C);
  csr_build<<<5 * H1C, 256, 0, stream>>>(Wv1,   H1C, cpack, cnnz, ROW_WV1);
  csr_build<<<5 * NN,  256, 0, stream>>>(Wout1, H1C, cpack, cnnz, ROW_WO1);
  csr_build<<<5 * H2C, 256, 0, stream>>>(Wv2,   H2C, cpack, cnnz, ROW_WV2);
  csr_build<<<5 * NN,  256, 0, stream>>>(Wout2, H2C, cpack, cnnz, ROW_WO2);
  init_prep<<<dim3(NN / 64, BATCH / 64), 256, 0, stream>>>(x_in, xb, tfT);

  for (int k = 0; k < 10; ++k) {
    const bool g1 = (k % 2 == 0);
    const int j = k / 2;
    const int H = g1 ? H1C : H2C;
    const bf16* BmT = g1 ? B1T : B2T;
    const int* idf = g1 ? idx1f : idx2f;
    const int* idm = g1 ? idx1m : idx2m;
    const int wv_off = g1 ? (ROW_WV1 + j * H1C) : (ROW_WV2 + j * H2C);
    const int wo_off = g1 ? (ROW_WO1 + j * NN)  : (ROW_WO2 + j * NN);
    const float* xcur = (k == 0) ? x_in : xf;

    // chS = x + x @ (S[k]-I)
    gemm_bt<<<dim3(NN / 128, BATCH / 128), 256, 0, stream>>>(
        xb, SmIT + (size_t)k * NN * NN, chS, chSb, xcur, BATCH, NN, NN);
    // t1 (fp8) = LLR of cn over phi-encoded tfT
    if (g1) cn_kernel<6, true><<<dim3(H, 1), 256, 0, stream>>>(tfT, idf, t1f8);
    else    cn_kernel<8, true><<<dim3(H, 1), 256, 0, stream>>>(tfT, idf, t1f8);
    // zTb = bf16( BmT @ chS^T )
    gemm_bt<<<dim3(BATCH / 128, H / 128), 256, 0, stream>>>(
        BmT, chSb, nullptr, (bf16*)zTb, nullptr, H, BATCH, NN);
    // t2p = phi( z + Wv @ t1 )
    sparse_wv<<<dim3(H, 1), 256, 0, stream>>>(zTb, t1f8, cpack, cnnz, wv_off, t2p);
    // t3 (bf16) = LLR of cn over phi-encoded t2p
    if (g1) cn_kernel<6, false><<<dim3(H, 1), 256, 0, stream>>>(t2p, idm, t3T);
    else    cn_kernel<8, false><<<dim3(H, 1), 256, 0, stream>>>(t2p, idm, t3T);
    // xpT = Wout @ t3
    sparse_wo<<<dim3(NN, 1), 256, 0, stream>>>(t3T, cpack, cnnz, wo_off, xpT);
    // epilogue
    fuse_out<<<dim3(NN / 64, BATCH / 64), 256, 0, stream>>>(
        xpT, chS, out + (size_t)k * BATCH * NN, xf, xb, tfT);
  }
}

// Round 11
// 1816.196 us; speedup vs baseline: 1.6359x; 1.0996x over previous
//
#include <hip/hip_runtime.h>
#include <hip/hip_bf16.h>
#include <stdint.h>
#include <stddef.h>

using bf16 = __hip_bfloat16;
typedef __attribute__((ext_vector_type(8))) short short8;
typedef __attribute__((ext_vector_type(2))) float f32x2;
typedef __attribute__((ext_vector_type(4))) float f32x4;
typedef __attribute__((ext_vector_type(4))) unsigned u32x4;

constexpr int BATCH = 2048;
constexpr int NN    = 1024;
constexpr int H1C   = 3072;
constexpr int H2C   = 4096;
constexpr int CAP   = 128;   // max nnz per sparse row

// CSR global row offsets
constexpr int ROW_WV1 = 0;                 // 5*3072 rows, len 3072
constexpr int ROW_WO1 = 5 * H1C;           // 5*1024 rows, len 3072
constexpr int ROW_WV2 = ROW_WO1 + 5 * NN;  // 5*4096 rows, len 4096
constexpr int ROW_WO2 = ROW_WV2 + 5 * H2C; // 5*1024 rows, len 4096
constexpr int ROWS_TOTAL = ROW_WO2 + 5 * NN; // 46080

__device__ __forceinline__ unsigned short f2bf(float f) {
  unsigned u = __float_as_uint(f);
  unsigned r = 0x7FFFu + ((u >> 16) & 1u);
  return (unsigned short)((u + r) >> 16);
}
__device__ __forceinline__ float bf2f(short s) {
  return __uint_as_float(((unsigned)(unsigned short)s) << 16);
}

// phi-domain encode of a pre-activation x (where t = tanh(x/2)):
//   value = sign(x) * phi(|x|),  phi(y) = log((1+e^-y)/(1-e^-y)) = -log(tanh(y/2))
//   x == 0  ->  +inf  (encodes t==0, excluded from products)
__device__ __forceinline__ unsigned short phi_enc(float x) {
  const float e = expf(-fabsf(x));
  const float phi = logf((1.f + e) / (1.f - e));  // +inf iff x==0
  return (unsigned short)(f2bf(phi) | (unsigned short)((__float_as_uint(x) >> 31) << 15));
}

__device__ __forceinline__ void gload16(const void* g, void* lds_base) {
  __builtin_amdgcn_global_load_lds(
      (const __attribute__((address_space(1))) void*)g,
      (__attribute__((address_space(3))) void*)lds_base, 16, 0, 0);
}

// ---- cn math body: given D phi-encoded short8 values, produce 8 signed LLR floats
template<int D>
__device__ __forceinline__ void cn_math(const short8* v, float* rs) {
  float s[8];
  unsigned sg[8];
  bool any[8];
#pragma unroll
  for (int e = 0; e < 8; ++e) { s[e] = 0.f; sg[e] = 0u; any[e] = false; }
#pragma unroll
  for (int d = 0; d < D; ++d) {
#pragma unroll
    for (int e = 0; e < 8; ++e) {
      const unsigned bits = (unsigned)(unsigned short)v[d][e];
      sg[e] ^= bits >> 15;
      const unsigned a = bits & 0x7FFFu;
      const bool nz = (a != 0x7F80u);   // +inf encodes t==0 (excluded)
      any[e] |= nz;
      s[e] += nz ? __uint_as_float(a << 16) : 0.f;
    }
  }
#pragma unroll
  for (int e = 0; e < 8; ++e) {
    const float y = fmaxf(s[e], 1.0000005e-6f);   // == clip(|u|, 0.999999)
    const float u = expf(-y);
    float r = logf((1.f + u) / (1.f - u));
    r = any[e] ? r : 0.f;
    rs[e] = __uint_as_float(__float_as_uint(r) | (sg[e] << 31));
  }
}

__device__ __forceinline__ void cn_store_fp8(const float* rs, uint8_t* dst) {
  int lo = 0, hi = 0;
  lo = __builtin_amdgcn_cvt_pk_fp8_f32(rs[0], rs[1], lo, false);
  lo = __builtin_amdgcn_cvt_pk_fp8_f32(rs[2], rs[3], lo, true);
  hi = __builtin_amdgcn_cvt_pk_fp8_f32(rs[4], rs[5], hi, false);
  hi = __builtin_amdgcn_cvt_pk_fp8_f32(rs[6], rs[7], hi, true);
  int2 o; o.x = lo; o.y = hi;
  *(int2*)dst = o;
}

// ---- bf16 MFMA GEMM (m97-structure): C[M,Nd] = A[M,K] @ BT[Nd,K]^T (+add), f32 and/or bf16 out
__global__ __launch_bounds__(256, 2) void gemm_bt(
    const bf16* __restrict__ A, const bf16* __restrict__ BT,
    float* __restrict__ C, bf16* __restrict__ Cb, const float* __restrict__ add,
    int M, int Nd, int K)
{
  __shared__ bf16 As[128 * 32];
  __shared__ bf16 Bs[128 * 32];
  const int tid  = threadIdx.x;
  const int lane = tid & 63;
  const int w    = tid >> 6;
  const int bn = blockIdx.x, bm = blockIdx.y;
  const int wm = (w >> 1) * 64, wn = (w & 1) * 64;
  const int l15 = lane & 15;
  const int lk  = (lane >> 4) * 8;
  const int ld4 = (lane >> 4) * 4;
  const int sr  = lane >> 2;
  const int kc  = (lane & 3) * 8;

  f32x4 acc[4][4];
#pragma unroll
  for (int i = 0; i < 4; ++i)
#pragma unroll
    for (int j = 0; j < 4; ++j)
#pragma unroll
      for (int e = 0; e < 4; ++e) acc[i][j][e] = 0.f;

  const size_t rA = (size_t)bm * 128;
  const size_t rB = (size_t)bn * 128;

  for (int kt = 0; kt < K; kt += 32) {
#pragma unroll
    for (int c = 0; c < 2; ++c) {
      const int slot = w * 2 + c;
      const int r = slot * 16 + sr;
      gload16(A  + (rA + r) * (size_t)K + kt + kc, &As[slot * 512]);
      gload16(BT + (rB + r) * (size_t)K + kt + kc, &Bs[slot * 512]);
    }
    __syncthreads();
    short8 af[4], bfr[4];
#pragma unroll
    for (int f = 0; f < 4; ++f) {
      af[f]  = *(const short8*)&As[(wm + f * 16 + l15) * 32 + lk];
      bfr[f] = *(const short8*)&Bs[(wn + f * 16 + l15) * 32 + lk];
    }
#pragma unroll
    for (int i = 0; i < 4; ++i)
#pragma unroll
      for (int j = 0; j < 4; ++j)
        acc[i][j] = __builtin_amdgcn_mfma_f32_16x16x32_bf16(af[i], bfr[j], acc[i][j], 0, 0, 0);
    __syncthreads();
  }

#pragma unroll
  for (int i = 0; i < 4; ++i) {
    const int row0 = bm * 128 + wm + i * 16 + ld4;
#pragma unroll
    for (int j = 0; j < 4; ++j) {
      const int col = bn * 128 + wn + j * 16 + l15;
#pragma unroll
      for (int e = 0; e < 4; ++e) {
        const size_t o = (size_t)(row0 + e) * Nd + col;
        float v = acc[i][j][e];
        if (add) v += add[o];
        if (C)  C[o] = v;
        if (Cb) Cb[o] = __float2bfloat16(v);
      }
    }
  }
}

// ---- merged: z-GEMM (blocks [0, gb)) + cn1 fp8 (blocks [gb, gb+H))
//      GEMM: zTb[M,2048] = bf16( A[M,K] @ BT[2048,K]^T );  cn1: t1f8 = cn(tfT, idx)
template<int D>
__global__ __launch_bounds__(256, 2) void zgemm_cn(
    const bf16* __restrict__ A, const bf16* __restrict__ BT, bf16* __restrict__ Cb,
    int K, int gb,
    const unsigned short* __restrict__ src, const int* __restrict__ idx,
    uint8_t* __restrict__ outf8)
{
  __shared__ bf16 As[128 * 32];
  __shared__ bf16 Bs[128 * 32];
  const int bid = blockIdx.x;
  if (bid < gb) {
    const int tid  = threadIdx.x;
    const int lane = tid & 63;
    const int w    = tid >> 6;
    const int bn = bid & 15;      // BATCH/128 = 16 tiles
    const int bm = bid >> 4;
    const int wm = (w >> 1) * 64, wn = (w & 1) * 64;
    const int l15 = lane & 15;
    const int lk  = (lane >> 4) * 8;
    const int ld4 = (lane >> 4) * 4;
    const int sr  = lane >> 2;
    const int kc  = (lane & 3) * 8;

    f32x4 acc[4][4];
#pragma unroll
    for (int i = 0; i < 4; ++i)
#pragma unroll
      for (int j = 0; j < 4; ++j)
#pragma unroll
        for (int e = 0; e < 4; ++e) acc[i][j][e] = 0.f;

    const size_t rA = (size_t)bm * 128;
    const size_t rB = (size_t)bn * 128;

    for (int kt = 0; kt < K; kt += 32) {
#pragma unroll
      for (int c = 0; c < 2; ++c) {
        const int slot = w * 2 + c;
        const int r = slot * 16 + sr;
        gload16(A  + (rA + r) * (size_t)K + kt + kc, &As[slot * 512]);
        gload16(BT + (rB + r) * (size_t)K + kt + kc, &Bs[slot * 512]);
      }
      __syncthreads();
      short8 af[4], bfr[4];
#pragma unroll
      for (int f = 0; f < 4; ++f) {
        af[f]  = *(const short8*)&As[(wm + f * 16 + l15) * 32 + lk];
        bfr[f] = *(const short8*)&Bs[(wn + f * 16 + l15) * 32 + lk];
      }
#pragma unroll
      for (int i = 0; i < 4; ++i)
#pragma unroll
        for (int j = 0; j < 4; ++j)
          acc[i][j] = __builtin_amdgcn_mfma_f32_16x16x32_bf16(af[i], bfr[j], acc[i][j], 0, 0, 0);
      __syncthreads();
    }

#pragma unroll
    for (int i = 0; i < 4; ++i) {
      const int row0 = bm * 128 + wm + i * 16 + ld4;
#pragma unroll
      for (int j = 0; j < 4; ++j) {
        const int col = bn * 128 + wn + j * 16 + l15;
#pragma unroll
        for (int e = 0; e < 4; ++e)
          Cb[(size_t)(row0 + e) * BATCH + col] = __float2bfloat16(acc[i][j][e]);
      }
    }
  } else {
    const int h = bid - gb;
    const int b = threadIdx.x * 8;
    const int* ir = idx + (size_t)h * D;
    int rows[D];
#pragma unroll
    for (int d = 0; d < D; ++d) rows[d] = ir[d];
    short8 v[D];
#pragma unroll
    for (int d = 0; d < D; ++d)
      v[d] = *(const short8*)(src + (size_t)rows[d] * BATCH + b);
    float rs[8];
    cn_math<D>(v, rs);
    cn_store_fp8(rs, outf8 + (size_t)h * BATCH + b);
  }
}

// ---- prep: SmIT[k][n][m] = bf16(S[k][m][n] - (m==n))
__global__ __launch_bounds__(256) void prep_smit(const float* __restrict__ S, bf16* __restrict__ out)
{
  __shared__ float ls[64][65];
  const int k = blockIdx.z;
  const int n0 = blockIdx.x * 64, m0 = blockIdx.y * 64;
  const float* Sk = S + (size_t)k * NN * NN;
  bf16* ok = out + (size_t)k * NN * NN;
  const int tc = threadIdx.x & 63, tr = threadIdx.x >> 6;
#pragma unroll
  for (int i = 0; i < 16; ++i) {
    const int r = tr + i * 4;
    ls[r][tc] = Sk[(size_t)(m0 + r) * NN + n0 + tc];
  }
  __syncthreads();
#pragma unroll
  for (int i = 0; i < 16; ++i) {
    const int r = tr + i * 4;
    float v = ls[tc][r] - ((m0 + tc) == (n0 + r) ? 1.f : 0.f);
    ok[(size_t)(n0 + r) * NN + m0 + tc] = __float2bfloat16(v);
  }
}

// ---- prep: out[h][n] = bf16(Bsrc[n][h]);  Bsrc is (NN, H)
__global__ __launch_bounds__(256) void prep_bt(const float* __restrict__ Bsrc, bf16* __restrict__ out, int H)
{
  __shared__ float ls[64][65];
  const int h0 = blockIdx.x * 64, n0 = blockIdx.y * 64;
  const int tc = threadIdx.x & 63, tr = threadIdx.x >> 6;
#pragma unroll
  for (int i = 0; i < 16; ++i) {
    const int r = tr + i * 4;
    ls[r][tc] = Bsrc[(size_t)(n0 + r) * H + h0 + tc];
  }
  __syncthreads();
#pragma unroll
  for (int i = 0; i < 16; ++i) {
    const int r = tr + i * 4;
    out[(size_t)(h0 + r) * NN + n0 + tc] = __float2bfloat16(ls[tc][r]);
  }
}

// ---- CSR build: one block per row, ordered compaction (deterministic)
//      packed entry: u32 = bf16(val)<<16 | col
__global__ __launch_bounds__(256) void csr_build(
    const float* __restrict__ W, int rowlen,
    unsigned* __restrict__ pack, int* __restrict__ nnz, int row_off)
{
  const int row = blockIdx.x;
  const float* wr = W + (size_t)row * rowlen;
  const size_t base = (size_t)(row_off + row) * CAP;
  __shared__ int wtot[4];
  __shared__ int cbase;
  if (threadIdx.x == 0) cbase = 0;
  __syncthreads();
  const int lane = threadIdx.x & 63, wv = threadIdx.x >> 6;
  for (int c0 = 0; c0 < rowlen; c0 += 256) {
    const int c = c0 + threadIdx.x;
    const float v = wr[c];
    const bool nz = (v != 0.f);
    const unsigned long long m = __ballot(nz);
    const int rank = __popcll(m & ((1ull << lane) - 1ull));
    if (lane == 0) wtot[wv] = __popcll(m);
    __syncthreads();
    int pre = cbase;
    for (int i = 0; i < wv; ++i) pre += wtot[i];
    if (nz) {
      const int p = pre + rank;
      if (p < CAP) pack[base + p] = ((unsigned)f2bf(v) << 16) | (unsigned)c;
    }
    __syncthreads();
    if (threadIdx.x == 0) cbase += wtot[0] + wtot[1] + wtot[2] + wtot[3];
    __syncthreads();
  }
  if (threadIdx.x == 0) nnz[row_off + row] = (cbase < CAP ? cbase : CAP);
}

// ---- standalone cn (fp8 out) for the second cn stage
template<int D>
__global__ __launch_bounds__(256) void cn_kernel(
    const unsigned short* __restrict__ src,  // (rows, BATCH) bf16 phi-encoded
    const int* __restrict__ idx,
    uint8_t* __restrict__ out)               // (H, BATCH) fp8 LLR
{
  const int h = blockIdx.x;
  const int b = threadIdx.x * 8;
  const int* ir = idx + (size_t)h * D;
  int rows[D];
#pragma unroll
  for (int d = 0; d < D; ++d) rows[d] = ir[d];
  short8 v[D];
#pragma unroll
  for (int d = 0; d < D; ++d)
    v[d] = *(const short8*)(src + (size_t)rows[d] * BATCH + b);
  float rs[8];
  cn_math<D>(v, rs);
  cn_store_fp8(rs, out + (size_t)h * BATCH + b);
}

// ---- sparse Wv apply: t2p[h,b] = phi_enc( z[h,b] + sum val*t1[col,b] ), t1 is fp8 e4m3
__global__ __launch_bounds__(256) void sparse_wv(
    const unsigned short* __restrict__ zb, const uint8_t* __restrict__ t1f8,
    const unsigned* __restrict__ pack, const int* __restrict__ nnz,
    int rowoff, unsigned short* __restrict__ t2p)
{
  const int h = blockIdx.x;
  const int b = threadIdx.x * 8;
  const int rg = rowoff + h;
  const unsigned* pr = pack + (size_t)rg * CAP;
  const int n = nnz[rg];
  const short8 z = *(const short8*)(zb + (size_t)h * BATCH + b);
  f32x4 a0, a1;
#pragma unroll
  for (int e = 0; e < 4; ++e) { a0[e] = bf2f(z[e]); a1[e] = bf2f(z[e + 4]); }
  int j = 0;
  for (; j + 4 <= n; j += 4) {
    const u32x4 w4 = *(const u32x4*)(pr + j);
    int2 t[4];
#pragma unroll
    for (int q = 0; q < 4; ++q)
      t[q] = *(const int2*)(t1f8 + (size_t)(w4[q] & 0xFFFFu) * BATCH + b);
#pragma unroll
    for (int q = 0; q < 4; ++q) {
      const float v = bf2f((short)(w4[q] >> 16));
      const f32x2 p01 = __builtin_amdgcn_cvt_pk_f32_fp8(t[q].x, false);
      const f32x2 p23 = __builtin_amdgcn_cvt_pk_f32_fp8(t[q].x, true);
      const f32x2 p45 = __builtin_amdgcn_cvt_pk_f32_fp8(t[q].y, false);
      const f32x2 p67 = __builtin_amdgcn_cvt_pk_f32_fp8(t[q].y, true);
      a0[0] += v * p01[0]; a0[1] += v * p01[1];
      a0[2] += v * p23[0]; a0[3] += v * p23[1];
      a1[0] += v * p45[0]; a1[1] += v * p45[1];
      a1[2] += v * p67[0]; a1[3] += v * p67[1];
    }
  }
  for (; j < n; ++j) {
    const unsigned pk = pr[j];
    const float v = bf2f((short)(pk >> 16));
    const int2 t = *(const int2*)(t1f8 + (size_t)(pk & 0xFFFFu) * BATCH + b);
    const f32x2 p01 = __builtin_amdgcn_cvt_pk_f32_fp8(t.x, false);
    const f32x2 p23 = __builtin_amdgcn_cvt_pk_f32_fp8(t.x, true);
    const f32x2 p45 = __builtin_amdgcn_cvt_pk_f32_fp8(t.y, false);
    const f32x2 p67 = __builtin_amdgcn_cvt_pk_f32_fp8(t.y, true);
    a0[0] += v * p01[0]; a0[1] += v * p01[1];
    a0[2] += v * p23[0]; a0[3] += v * p23[1];
    a1[0] += v * p45[0]; a1[1] += v * p45[1];
    a1[2] += v * p67[0]; a1[3] += v * p67[1];
  }
  short8 ov;
#pragma unroll
  for (int e = 0; e < 4; ++e) {
    ov[e]     = (short)phi_enc(a0[e]);   // t2 = tanh(0.5*a) -> phi domain
    ov[e + 4] = (short)phi_enc(a1[e]);
  }
  *(short8*)(t2p + (size_t)h * BATCH + b) = ov;
}

// ---- sparse Wout apply: xp[n,b] = sum val*t3[col,b], t3 fp8 e4m3
__global__ __launch_bounds__(256) void sparse_wo(
    const uint8_t* __restrict__ t3f8,
    const unsigned* __restrict__ pack, const int* __restrict__ nnz,
    int rowoff, float* __restrict__ xp)
{
  const int nrow = blockIdx.x;
  const int b = threadIdx.x * 8;
  const int rg = rowoff + nrow;
  const unsigned* pr = pack + (size_t)rg * CAP;
  const int cnt = nnz[rg];
  f32x4 a0 = {0.f, 0.f, 0.f, 0.f};
  f32x4 a1 = {0.f, 0.f, 0.f, 0.f};
  int j = 0;
  for (; j + 4 <= cnt; j += 4) {
    const u32x4 w4 = *(const u32x4*)(pr + j);
    int2 t[4];
#pragma unroll
    for (int q = 0; q < 4; ++q)
      t[q] = *(const int2*)(t3f8 + (size_t)(w4[q] & 0xFFFFu) * BATCH + b);
#pragma unroll
    for (int q = 0; q < 4; ++q) {
      const float v = bf2f((short)(w4[q] >> 16));
      const f32x2 p01 = __builtin_amdgcn_cvt_pk_f32_fp8(t[q].x, false);
      const f32x2 p23 = __builtin_amdgcn_cvt_pk_f32_fp8(t[q].x, true);
      const f32x2 p45 = __builtin_amdgcn_cvt_pk_f32_fp8(t[q].y, false);
      const f32x2 p67 = __builtin_amdgcn_cvt_pk_f32_fp8(t[q].y, true);
      a0[0] += v * p01[0]; a0[1] += v * p01[1];
      a0[2] += v * p23[0]; a0[3] += v * p23[1];
      a1[0] += v * p45[0]; a1[1] += v * p45[1];
      a1[2] += v * p67[0]; a1[3] += v * p67[1];
    }
  }
  for (; j < cnt; ++j) {
    const unsigned pk = pr[j];
    const float v = bf2f((short)(pk >> 16));
    const int2 t = *(const int2*)(t3f8 + (size_t)(pk & 0xFFFFu) * BATCH + b);
    const f32x2 p01 = __builtin_amdgcn_cvt_pk_f32_fp8(t.x, false);
    const f32x2 p23 = __builtin_amdgcn_cvt_pk_f32_fp8(t.x, true);
    const f32x2 p45 = __builtin_amdgcn_cvt_pk_f32_fp8(t.y, false);
    const f32x2 p67 = __builtin_amdgcn_cvt_pk_f32_fp8(t.y, true);
    a0[0] += v * p01[0]; a0[1] += v * p01[1];
    a0[2] += v * p23[0]; a0[3] += v * p23[1];
    a1[0] += v * p45[0]; a1[1] += v * p45[1];
    a1[2] += v * p67[0]; a1[3] += v * p67[1];
  }
  float* orow = xp + (size_t)nrow * BATCH + b;
  *(f32x4*)orow = a0;
  *(f32x4*)(orow + 4) = a1;
}

// ---- fused epilogue: x_new = chS + xp^T; sigmoid->out, x f32, x bf16 (B,N), phi(x)->tfT (N,B)
__global__ __launch_bounds__(256) void fuse_out(
    const float* __restrict__ xpT,
    const float* __restrict__ chS,
    float* __restrict__ dout,
    float* __restrict__ xf,
    bf16* __restrict__ xb,
    unsigned short* __restrict__ tfT)
{
  __shared__ float lc[64][65];
  __shared__ float lx[64][65];
  const int n0 = blockIdx.x * 64, b0 = blockIdx.y * 64;
  const int tc = threadIdx.x & 63, tr = threadIdx.x >> 6;
#pragma unroll
  for (int i = 0; i < 16; ++i) {
    const int r = tr + i * 4;
    lc[r][tc] = chS[(size_t)(b0 + r) * NN + n0 + tc];
    lx[r][tc] = xpT[(size_t)(n0 + r) * BATCH + b0 + tc];
  }
  __syncthreads();
#pragma unroll
  for (int i = 0; i < 16; ++i) {
    const int r = tr + i * 4;
    const float v = lc[r][tc] + lx[tc][r];
    const size_t o = (size_t)(b0 + r) * NN + n0 + tc;
    dout[o] = 1.f / (1.f + expf(-v));
    xf[o] = v;
    xb[o] = __float2bfloat16(v);
  }
#pragma unroll
  for (int i = 0; i < 16; ++i) {
    const int r = tr + i * 4;
    const float v = lc[tc][r] + lx[r][tc];
    tfT[(size_t)(n0 + r) * BATCH + b0 + tc] = phi_enc(v);
  }
}

// ---- initial prep (k=0): from x (B,N) make xb (B,N) and phi(x)->tfT (N,B)
__global__ __launch_bounds__(256) void init_prep(
    const float* __restrict__ x, bf16* __restrict__ xb, unsigned short* __restrict__ tfT)
{
  __shared__ float ls[64][65];
  const int n0 = blockIdx.x * 64, b0 = blockIdx.y * 64;
  const int tc = threadIdx.x & 63, tr = threadIdx.x >> 6;
#pragma unroll
  for (int i = 0; i < 16; ++i) {
    const int r = tr + i * 4;
    const size_t o = (size_t)(b0 + r) * NN + n0 + tc;
    const float v = x[o];
    ls[r][tc] = v;
    xb[o] = __float2bfloat16(v);
  }
  __syncthreads();
#pragma unroll
  for (int i = 0; i < 16; ++i) {
    const int r = tr + i * 4;
    tfT[(size_t)(n0 + r) * BATCH + b0 + tc] = phi_enc(ls[tc][r]);
  }
}

extern "C" void kernel_launch(void* const* d_in, const int* in_sizes, int n_in,
                              void* d_out, int out_size, void* d_ws, size_t ws_size,
                              hipStream_t stream)
{
  const float* x_in  = (const float*)d_in[0];
  const float* S     = (const float*)d_in[1];
  const float* B1    = (const float*)d_in[2];
  const float* B2    = (const float*)d_in[3];
  const float* Wv1   = (const float*)d_in[4];
  const float* Wout1 = (const float*)d_in[5];
  const float* Wv2   = (const float*)d_in[6];
  const float* Wout2 = (const float*)d_in[7];
  const int* idx1f   = (const int*)d_in[8];
  const int* idx1m   = (const int*)d_in[9];
  const int* idx2f   = (const int*)d_in[10];
  const int* idx2m   = (const int*)d_in[11];
  float* out = (float*)d_out;

  uint8_t* p = (uint8_t*)d_ws;
  auto alloc = [&](size_t bytes) -> void* {
    void* r = p;
    p += (bytes + 255) & ~(size_t)255;
    return r;
  };
  bf16*  SmIT = (bf16*)alloc((size_t)10 * NN * NN * sizeof(bf16));
  bf16*  B1T  = (bf16*)alloc((size_t)H1C * NN * sizeof(bf16));
  bf16*  B2T  = (bf16*)alloc((size_t)H2C * NN * sizeof(bf16));
  unsigned* cpack = (unsigned*)alloc((size_t)ROWS_TOTAL * CAP * sizeof(unsigned));
  int*   cnnz  = (int*)alloc((size_t)ROWS_TOTAL * sizeof(int));
  float* xf   = (float*)alloc((size_t)BATCH * NN * sizeof(float));
  bf16*  xb   = (bf16*)alloc((size_t)BATCH * NN * sizeof(bf16));
  unsigned short* tfT = (unsigned short*)alloc((size_t)NN * BATCH * sizeof(unsigned short)); // phi(x)
  float* chS  = (float*)alloc((size_t)BATCH * NN * sizeof(float));
  bf16*  chSb = (bf16*)alloc((size_t)BATCH * NN * sizeof(bf16));
  uint8_t* t1f8 = (uint8_t*)alloc((size_t)H2C * BATCH);                                       // fp8 t1
  uint8_t* t3f8 = (uint8_t*)alloc((size_t)H2C * BATCH);                                       // fp8 t3
  unsigned short* zTb = (unsigned short*)alloc((size_t)H2C * BATCH * sizeof(unsigned short)); // bf16 z
  unsigned short* t2p = (unsigned short*)alloc((size_t)H2C * BATCH * sizeof(unsigned short)); // phi(t2)
  float* xpT  = (float*)alloc((size_t)NN * BATCH * sizeof(float));
  (void)ws_size; (void)in_sizes; (void)n_in; (void)out_size;

  // --- per-call prep
  prep_smit<<<dim3(NN / 64, NN / 64, 10), 256, 0, stream>>>(S, SmIT);
  prep_bt<<<dim3(H1C / 64, NN / 64), 256, 0, stream>>>(B1, B1T, H1C);
  prep_bt<<<dim3(H2C / 64, NN / 64), 256, 0, stream>>>(B2, B2T, H2C);
  csr_build<<<5 * H1C, 256, 0, stream>>>(Wv1,   H1C, cpack, cnnz, ROW_WV1);
  csr_build<<<5 * NN,  256, 0, stream>>>(Wout1, H1C, cpack, cnnz, ROW_WO1);
  csr_build<<<5 * H2C, 256, 0, stream>>>(Wv2,   H2C, cpack, cnnz, ROW_WV2);
  csr_build<<<5 * NN,  256, 0, stream>>>(Wout2, H2C, cpack, cnnz, ROW_WO2);
  init_prep<<<dim3(NN / 64, BATCH / 64), 256, 0, stream>>>(x_in, xb, tfT);

  for (int k = 0; k < 10; ++k) {
    const bool g1 = (k % 2 == 0);
    const int j = k / 2;
    const int H = g1 ? H1C : H2C;
    const bf16* BmT = g1 ? B1T : B2T;
    const int* idf = g1 ? idx1f : idx2f;
    const int* idm = g1 ? idx1m : idx2m;
    const int wv_off = g1 ? (ROW_WV1 + j * H1C) : (ROW_WV2 + j * H2C);
    const int wo_off = g1 ? (ROW_WO1 + j * NN)  : (ROW_WO2 + j * NN);
    const float* xcur = (k == 0) ? x_in : xf;
    const int gb = (BATCH / 128) * (H / 128);   // z-GEMM blocks (bn fast, 16 wide)

    // chS = x + x @ (S[k]-I)
    gemm_bt<<<dim3(NN / 128, BATCH / 128), 256, 0, stream>>>(
        xb, SmIT + (size_t)k * NN * NN, chS, chSb, xcur, BATCH, NN, NN);
    // merged: zTb = bf16(BmT @ chS^T)  ||  t1f8 = cn(tfT, idf)
    if (g1) zgemm_cn<6><<<gb + H, 256, 0, stream>>>(BmT, chSb, (bf16*)zTb, NN, gb, tfT, idf, t1f8);
    else    zgemm_cn<8><<<gb + H, 256, 0, stream>>>(BmT, chSb, (bf16*)zTb, NN, gb, tfT, idf, t1f8);
    // t2p = phi( z + Wv @ t1 )
    sparse_wv<<<dim3(H, 1), 256, 0, stream>>>(zTb, t1f8, cpack, cnnz, wv_off, t2p);
    // t3f8 = cn(t2p, idm)
    if (g1) cn_kernel<6><<<dim3(H, 1), 256, 0, stream>>>(t2p, idm, t3f8);
    else    cn_kernel<8><<<dim3(H, 1), 256, 0, stream>>>(t2p, idm, t3f8);
    // xpT = Wout @ t3
    sparse_wo<<<dim3(NN, 1), 256, 0, stream>>>(t3f8, cpack, cnnz, wo_off, xpT);
    // epilogue
    fuse_out<<<dim3(NN / 64, BATCH / 64), 256, 0, stream>>>(
        xpT, chS, out + (size_t)k * BATCH * NN, xf, xb, tfT);
  }
}

// Round 12
// 1641.578 us; speedup vs baseline: 1.8099x; 1.1064x over previous
//
#include <hip/hip_runtime.h>
#include <hip/hip_bf16.h>
#include <stdint.h>
#include <stddef.h>

using bf16 = __hip_bfloat16;
typedef __attribute__((ext_vector_type(8))) short short8;
typedef __attribute__((ext_vector_type(2))) float f32x2;
typedef __attribute__((ext_vector_type(4))) float f32x4;
typedef __attribute__((ext_vector_type(4))) unsigned u32x4;

constexpr int BATCH = 2048;
constexpr int NN    = 1024;
constexpr int H1C   = 3072;
constexpr int H2C   = 4096;
constexpr int CAP   = 128;   // max nnz per sparse row

// CSR global row offsets
constexpr int ROW_WV1 = 0;                 // 5*3072 rows, len 3072
constexpr int ROW_WO1 = 5 * H1C;           // 5*1024 rows, len 3072
constexpr int ROW_WV2 = ROW_WO1 + 5 * NN;  // 5*4096 rows, len 4096
constexpr int ROW_WO2 = ROW_WV2 + 5 * H2C; // 5*1024 rows, len 4096
constexpr int ROWS_TOTAL = ROW_WO2 + 5 * NN; // 46080

__device__ __forceinline__ unsigned short f2bf(float f) {
  unsigned u = __float_as_uint(f);
  unsigned r = 0x7FFFu + ((u >> 16) & 1u);
  return (unsigned short)((u + r) >> 16);
}
__device__ __forceinline__ float bf2f(short s) {
  return __uint_as_float(((unsigned)(unsigned short)s) << 16);
}

// phi-domain encode of a pre-activation x (where t = tanh(x/2)):
//   value = sign(x) * phi(|x|),  phi(y) = log((1+e^-y)/(1-e^-y)) = -log(tanh(y/2))
//   x == 0  ->  +inf  (encodes t==0, excluded from products)
__device__ __forceinline__ unsigned short phi_enc(float x) {
  const float e = expf(-fabsf(x));
  const float phi = logf((1.f + e) / (1.f - e));  // +inf iff x==0
  return (unsigned short)(f2bf(phi) | (unsigned short)((__float_as_uint(x) >> 31) << 15));
}

__device__ __forceinline__ void gload16(const void* g, void* lds_base) {
  __builtin_amdgcn_global_load_lds(
      (const __attribute__((address_space(1))) void*)g,
      (__attribute__((address_space(3))) void*)lds_base, 16, 0, 0);
}

// ---- cn math body: given D phi-encoded short8 values, produce 8 signed LLR floats
template<int D>
__device__ __forceinline__ void cn_math(const short8* v, float* rs) {
  float s[8];
  unsigned sg[8];
  bool any[8];
#pragma unroll
  for (int e = 0; e < 8; ++e) { s[e] = 0.f; sg[e] = 0u; any[e] = false; }
#pragma unroll
  for (int d = 0; d < D; ++d) {
#pragma unroll
    for (int e = 0; e < 8; ++e) {
      const unsigned bits = (unsigned)(unsigned short)v[d][e];
      sg[e] ^= bits >> 15;
      const unsigned a = bits & 0x7FFFu;
      const bool nz = (a != 0x7F80u);   // +inf encodes t==0 (excluded)
      any[e] |= nz;
      s[e] += nz ? __uint_as_float(a << 16) : 0.f;
    }
  }
#pragma unroll
  for (int e = 0; e < 8; ++e) {
    const float y = fmaxf(s[e], 1.0000005e-6f);   // == clip(|u|, 0.999999)
    const float u = expf(-y);
    float r = logf((1.f + u) / (1.f - u));
    r = any[e] ? r : 0.f;
    rs[e] = __uint_as_float(__float_as_uint(r) | (sg[e] << 31));
  }
}

__device__ __forceinline__ void cn_store_fp8(const float* rs, uint8_t* dst) {
  int lo = 0, hi = 0;
  lo = __builtin_amdgcn_cvt_pk_fp8_f32(rs[0], rs[1], lo, false);
  lo = __builtin_amdgcn_cvt_pk_fp8_f32(rs[2], rs[3], lo, true);
  hi = __builtin_amdgcn_cvt_pk_fp8_f32(rs[4], rs[5], hi, false);
  hi = __builtin_amdgcn_cvt_pk_fp8_f32(rs[6], rs[7], hi, true);
  int2 o; o.x = lo; o.y = hi;
  *(int2*)dst = o;
}

// ---- bf16 MFMA GEMM (m97-structure): C[M,Nd] = A[M,K] @ BT[Nd,K]^T (+add), f32 and/or bf16 out
__global__ __launch_bounds__(256, 2) void gemm_bt(
    const bf16* __restrict__ A, const bf16* __restrict__ BT,
    float* __restrict__ C, bf16* __restrict__ Cb, const float* __restrict__ add,
    int M, int Nd, int K)
{
  __shared__ bf16 As[128 * 32];
  __shared__ bf16 Bs[128 * 32];
  const int tid  = threadIdx.x;
  const int lane = tid & 63;
  const int w    = tid >> 6;
  const int bn = blockIdx.x, bm = blockIdx.y;
  const int wm = (w >> 1) * 64, wn = (w & 1) * 64;
  const int l15 = lane & 15;
  const int lk  = (lane >> 4) * 8;
  const int ld4 = (lane >> 4) * 4;
  const int sr  = lane >> 2;
  const int kc  = (lane & 3) * 8;

  f32x4 acc[4][4];
#pragma unroll
  for (int i = 0; i < 4; ++i)
#pragma unroll
    for (int j = 0; j < 4; ++j)
#pragma unroll
      for (int e = 0; e < 4; ++e) acc[i][j][e] = 0.f;

  const size_t rA = (size_t)bm * 128;
  const size_t rB = (size_t)bn * 128;

  for (int kt = 0; kt < K; kt += 32) {
#pragma unroll
    for (int c = 0; c < 2; ++c) {
      const int slot = w * 2 + c;
      const int r = slot * 16 + sr;
      gload16(A  + (rA + r) * (size_t)K + kt + kc, &As[slot * 512]);
      gload16(BT + (rB + r) * (size_t)K + kt + kc, &Bs[slot * 512]);
    }
    __syncthreads();
    short8 af[4], bfr[4];
#pragma unroll
    for (int f = 0; f < 4; ++f) {
      af[f]  = *(const short8*)&As[(wm + f * 16 + l15) * 32 + lk];
      bfr[f] = *(const short8*)&Bs[(wn + f * 16 + l15) * 32 + lk];
    }
#pragma unroll
    for (int i = 0; i < 4; ++i)
#pragma unroll
      for (int j = 0; j < 4; ++j)
        acc[i][j] = __builtin_amdgcn_mfma_f32_16x16x32_bf16(af[i], bfr[j], acc[i][j], 0, 0, 0);
    __syncthreads();
  }

#pragma unroll
  for (int i = 0; i < 4; ++i) {
    const int row0 = bm * 128 + wm + i * 16 + ld4;
#pragma unroll
    for (int j = 0; j < 4; ++j) {
      const int col = bn * 128 + wn + j * 16 + l15;
#pragma unroll
      for (int e = 0; e < 4; ++e) {
        const size_t o = (size_t)(row0 + e) * Nd + col;
        float v = acc[i][j][e];
        if (add) v += add[o];
        if (C)  C[o] = v;
        if (Cb) Cb[o] = __float2bfloat16(v);
      }
    }
  }
}

// ---- BM=64 x BN=128 GEMM variant (2 waves, 128 threads): doubles grid size for
//      underfilled shapes (chS: M=2048, N=1024 -> 256 blocks instead of 128).
//      Identical per-fragment MFMA sum order -> bit-identical results.
__global__ __launch_bounds__(128, 4) void gemm_bt64(
    const bf16* __restrict__ A, const bf16* __restrict__ BT,
    float* __restrict__ C, bf16* __restrict__ Cb, const float* __restrict__ add,
    int M, int Nd, int K)
{
  __shared__ bf16 As[64 * 32];
  __shared__ bf16 Bs[128 * 32];
  const int tid  = threadIdx.x;
  const int lane = tid & 63;
  const int w    = tid >> 6;          // 0..1
  const int bn = blockIdx.x, bm = blockIdx.y;
  const int wn = w * 64;
  const int l15 = lane & 15;
  const int lk  = (lane >> 4) * 8;
  const int ld4 = (lane >> 4) * 4;
  const int sr  = lane >> 2;
  const int kc  = (lane & 3) * 8;

  f32x4 acc[4][4];
#pragma unroll
  for (int i = 0; i < 4; ++i)
#pragma unroll
    for (int j = 0; j < 4; ++j)
#pragma unroll
      for (int e = 0; e < 4; ++e) acc[i][j][e] = 0.f;

  const size_t rA = (size_t)bm * 64;
  const size_t rB = (size_t)bn * 128;

  for (int kt = 0; kt < K; kt += 32) {
#pragma unroll
    for (int c = 0; c < 2; ++c) {       // A: 4 slots of 16 rows, 2 per wave
      const int slot = w * 2 + c;
      const int r = slot * 16 + sr;
      gload16(A + (rA + r) * (size_t)K + kt + kc, &As[slot * 512]);
    }
#pragma unroll
    for (int c = 0; c < 4; ++c) {       // B: 8 slots, 4 per wave
      const int slot = w * 4 + c;
      const int r = slot * 16 + sr;
      gload16(BT + (rB + r) * (size_t)K + kt + kc, &Bs[slot * 512]);
    }
    __syncthreads();
    short8 af[4], bfr[4];
#pragma unroll
    for (int f = 0; f < 4; ++f) {
      af[f]  = *(const short8*)&As[(f * 16 + l15) * 32 + lk];
      bfr[f] = *(const short8*)&Bs[(wn + f * 16 + l15) * 32 + lk];
    }
#pragma unroll
    for (int i = 0; i < 4; ++i)
#pragma unroll
      for (int j = 0; j < 4; ++j)
        acc[i][j] = __builtin_amdgcn_mfma_f32_16x16x32_bf16(af[i], bfr[j], acc[i][j], 0, 0, 0);
    __syncthreads();
  }

#pragma unroll
  for (int i = 0; i < 4; ++i) {
    const int row0 = bm * 64 + i * 16 + ld4;
#pragma unroll
    for (int j = 0; j < 4; ++j) {
      const int col = bn * 128 + wn + j * 16 + l15;
#pragma unroll
      for (int e = 0; e < 4; ++e) {
        const size_t o = (size_t)(row0 + e) * Nd + col;
        float v = acc[i][j][e];
        if (add) v += add[o];
        if (C)  C[o] = v;
        if (Cb) Cb[o] = __float2bfloat16(v);
      }
    }
  }
}

// ---- merged: z-GEMM (blocks [0, gb)) + cn1 fp8 (blocks [gb, gb+H))
//      GEMM: zTb[M,2048] = bf16( A[M,K] @ BT[2048,K]^T );  cn1: t1f8 = cn(tfT, idx)
template<int D>
__global__ __launch_bounds__(256, 2) void zgemm_cn(
    const bf16* __restrict__ A, const bf16* __restrict__ BT, bf16* __restrict__ Cb,
    int K, int gb,
    const unsigned short* __restrict__ src, const int* __restrict__ idx,
    uint8_t* __restrict__ outf8)
{
  __shared__ bf16 As[128 * 32];
  __shared__ bf16 Bs[128 * 32];
  const int bid = blockIdx.x;
  if (bid < gb) {
    const int tid  = threadIdx.x;
    const int lane = tid & 63;
    const int w    = tid >> 6;
    const int bn = bid & 15;      // BATCH/128 = 16 tiles
    const int bm = bid >> 4;
    const int wm = (w >> 1) * 64, wn = (w & 1) * 64;
    const int l15 = lane & 15;
    const int lk  = (lane >> 4) * 8;
    const int ld4 = (lane >> 4) * 4;
    const int sr  = lane >> 2;
    const int kc  = (lane & 3) * 8;

    f32x4 acc[4][4];
#pragma unroll
    for (int i = 0; i < 4; ++i)
#pragma unroll
      for (int j = 0; j < 4; ++j)
#pragma unroll
        for (int e = 0; e < 4; ++e) acc[i][j][e] = 0.f;

    const size_t rA = (size_t)bm * 128;
    const size_t rB = (size_t)bn * 128;

    for (int kt = 0; kt < K; kt += 32) {
#pragma unroll
      for (int c = 0; c < 2; ++c) {
        const int slot = w * 2 + c;
        const int r = slot * 16 + sr;
        gload16(A  + (rA + r) * (size_t)K + kt + kc, &As[slot * 512]);
        gload16(BT + (rB + r) * (size_t)K + kt + kc, &Bs[slot * 512]);
      }
      __syncthreads();
      short8 af[4], bfr[4];
#pragma unroll
      for (int f = 0; f < 4; ++f) {
        af[f]  = *(const short8*)&As[(wm + f * 16 + l15) * 32 + lk];
        bfr[f] = *(const short8*)&Bs[(wn + f * 16 + l15) * 32 + lk];
      }
#pragma unroll
      for (int i = 0; i < 4; ++i)
#pragma unroll
        for (int j = 0; j < 4; ++j)
          acc[i][j] = __builtin_amdgcn_mfma_f32_16x16x32_bf16(af[i], bfr[j], acc[i][j], 0, 0, 0);
      __syncthreads();
    }

#pragma unroll
    for (int i = 0; i < 4; ++i) {
      const int row0 = bm * 128 + wm + i * 16 + ld4;
#pragma unroll
      for (int j = 0; j < 4; ++j) {
        const int col = bn * 128 + wn + j * 16 + l15;
#pragma unroll
        for (int e = 0; e < 4; ++e)
          Cb[(size_t)(row0 + e) * BATCH + col] = __float2bfloat16(acc[i][j][e]);
      }
    }
  } else {
    const int h = bid - gb;
    const int b = threadIdx.x * 8;
    const int* ir = idx + (size_t)h * D;
    int rows[D];
#pragma unroll
    for (int d = 0; d < D; ++d) rows[d] = ir[d];
    short8 v[D];
#pragma unroll
    for (int d = 0; d < D; ++d)
      v[d] = *(const short8*)(src + (size_t)rows[d] * BATCH + b);
    float rs[8];
    cn_math<D>(v, rs);
    cn_store_fp8(rs, outf8 + (size_t)h * BATCH + b);
  }
}

// ---- prep: SmIT[k][n][m] = bf16(S[k][m][n] - (m==n))
__global__ __launch_bounds__(256) void prep_smit(const float* __restrict__ S, bf16* __restrict__ out)
{
  __shared__ float ls[64][65];
  const int k = blockIdx.z;
  const int n0 = blockIdx.x * 64, m0 = blockIdx.y * 64;
  const float* Sk = S + (size_t)k * NN * NN;
  bf16* ok = out + (size_t)k * NN * NN;
  const int tc = threadIdx.x & 63, tr = threadIdx.x >> 6;
#pragma unroll
  for (int i = 0; i < 16; ++i) {
    const int r = tr + i * 4;
    ls[r][tc] = Sk[(size_t)(m0 + r) * NN + n0 + tc];
  }
  __syncthreads();
#pragma unroll
  for (int i = 0; i < 16; ++i) {
    const int r = tr + i * 4;
    float v = ls[tc][r] - ((m0 + tc) == (n0 + r) ? 1.f : 0.f);
    ok[(size_t)(n0 + r) * NN + m0 + tc] = __float2bfloat16(v);
  }
}

// ---- prep: out[h][n] = bf16(Bsrc[n][h]);  Bsrc is (NN, H)
__global__ __launch_bounds__(256) void prep_bt(const float* __restrict__ Bsrc, bf16* __restrict__ out, int H)
{
  __shared__ float ls[64][65];
  const int h0 = blockIdx.x * 64, n0 = blockIdx.y * 64;
  const int tc = threadIdx.x & 63, tr = threadIdx.x >> 6;
#pragma unroll
  for (int i = 0; i < 16; ++i) {
    const int r = tr + i * 4;
    ls[r][tc] = Bsrc[(size_t)(n0 + r) * H + h0 + tc];
  }
  __syncthreads();
#pragma unroll
  for (int i = 0; i < 16; ++i) {
    const int r = tr + i * 4;
    out[(size_t)(h0 + r) * NN + n0 + tc] = __float2bfloat16(ls[tc][r]);
  }
}

// ---- CSR build, vectorized: one block per row, f32x4 loads (1024 cols/chunk),
//      deterministic column-order compaction via 4 ballots + wave prefix.
//      packed entry: u32 = bf16(val)<<16 | col
__global__ __launch_bounds__(256) void csr_build(
    const float* __restrict__ W, int rowlen,
    unsigned* __restrict__ pack, int* __restrict__ nnz, int row_off)
{
  const int row = blockIdx.x;
  const float* wr = W + (size_t)row * rowlen;
  const size_t base = (size_t)(row_off + row) * CAP;
  __shared__ int wtot[4];
  __shared__ int cbase;
  if (threadIdx.x == 0) cbase = 0;
  __syncthreads();
  const int lane = threadIdx.x & 63, wv = threadIdx.x >> 6;
  const unsigned long long lanemask = (1ull << lane) - 1ull;
  for (int c0 = 0; c0 < rowlen; c0 += 1024) {
    const int c = c0 + threadIdx.x * 4;
    const f32x4 v = *(const f32x4*)(wr + c);
    unsigned long long m[4];
#pragma unroll
    for (int e = 0; e < 4; ++e) m[e] = __ballot(v[e] != 0.f);
    int pre_lane = 0;
#pragma unroll
    for (int e = 0; e < 4; ++e) pre_lane += __popcll(m[e] & lanemask);
    if (lane == 0)
      wtot[wv] = __popcll(m[0]) + __popcll(m[1]) + __popcll(m[2]) + __popcll(m[3]);
    __syncthreads();
    int pre = cbase + pre_lane;
    for (int i = 0; i < wv; ++i) pre += wtot[i];
    int off = 0;
#pragma unroll
    for (int e = 0; e < 4; ++e) {
      if (v[e] != 0.f) {
        const int p = pre + off;
        if (p < CAP) pack[base + p] = ((unsigned)f2bf(v[e]) << 16) | (unsigned)(c + e);
        ++off;
      }
    }
    __syncthreads();
    if (threadIdx.x == 0) cbase += wtot[0] + wtot[1] + wtot[2] + wtot[3];
    __syncthreads();
  }
  if (threadIdx.x == 0) nnz[row_off + row] = (cbase < CAP ? cbase : CAP);
}

// ---- standalone cn (fp8 out) for the second cn stage
template<int D>
__global__ __launch_bounds__(256) void cn_kernel(
    const unsigned short* __restrict__ src,  // (rows, BATCH) bf16 phi-encoded
    const int* __restrict__ idx,
    uint8_t* __restrict__ out)               // (H, BATCH) fp8 LLR
{
  const int h = blockIdx.x;
  const int b = threadIdx.x * 8;
  const int* ir = idx + (size_t)h * D;
  int rows[D];
#pragma unroll
  for (int d = 0; d < D; ++d) rows[d] = ir[d];
  short8 v[D];
#pragma unroll
  for (int d = 0; d < D; ++d)
    v[d] = *(const short8*)(src + (size_t)rows[d] * BATCH + b);
  float rs[8];
  cn_math<D>(v, rs);
  cn_store_fp8(rs, out + (size_t)h * BATCH + b);
}

// ---- sparse Wv apply: t2p[h,b] = phi_enc( z[h,b] + sum val*t1[col,b] ), t1 is fp8 e4m3
__global__ __launch_bounds__(256) void sparse_wv(
    const unsigned short* __restrict__ zb, const uint8_t* __restrict__ t1f8,
    const unsigned* __restrict__ pack, const int* __restrict__ nnz,
    int rowoff, unsigned short* __restrict__ t2p)
{
  const int h = blockIdx.x;
  const int b = threadIdx.x * 8;
  const int rg = rowoff + h;
  const unsigned* pr = pack + (size_t)rg * CAP;
  const int n = nnz[rg];
  const short8 z = *(const short8*)(zb + (size_t)h * BATCH + b);
  f32x4 a0, a1;
#pragma unroll
  for (int e = 0; e < 4; ++e) { a0[e] = bf2f(z[e]); a1[e] = bf2f(z[e + 4]); }
  int j = 0;
  for (; j + 4 <= n; j += 4) {
    const u32x4 w4 = *(const u32x4*)(pr + j);
    int2 t[4];
#pragma unroll
    for (int q = 0; q < 4; ++q)
      t[q] = *(const int2*)(t1f8 + (size_t)(w4[q] & 0xFFFFu) * BATCH + b);
#pragma unroll
    for (int q = 0; q < 4; ++q) {
      const float v = bf2f((short)(w4[q] >> 16));
      const f32x2 p01 = __builtin_amdgcn_cvt_pk_f32_fp8(t[q].x, false);
      const f32x2 p23 = __builtin_amdgcn_cvt_pk_f32_fp8(t[q].x, true);
      const f32x2 p45 = __builtin_amdgcn_cvt_pk_f32_fp8(t[q].y, false);
      const f32x2 p67 = __builtin_amdgcn_cvt_pk_f32_fp8(t[q].y, true);
      a0[0] += v * p01[0]; a0[1] += v * p01[1];
      a0[2] += v * p23[0]; a0[3] += v * p23[1];
      a1[0] += v * p45[0]; a1[1] += v * p45[1];
      a1[2] += v * p67[0]; a1[3] += v * p67[1];
    }
  }
  for (; j < n; ++j) {
    const unsigned pk = pr[j];
    const float v = bf2f((short)(pk >> 16));
    const int2 t = *(const int2*)(t1f8 + (size_t)(pk & 0xFFFFu) * BATCH + b);
    const f32x2 p01 = __builtin_amdgcn_cvt_pk_f32_fp8(t.x, false);
    const f32x2 p23 = __builtin_amdgcn_cvt_pk_f32_fp8(t.x, true);
    const f32x2 p45 = __builtin_amdgcn_cvt_pk_f32_fp8(t.y, false);
    const f32x2 p67 = __builtin_amdgcn_cvt_pk_f32_fp8(t.y, true);
    a0[0] += v * p01[0]; a0[1] += v * p01[1];
    a0[2] += v * p23[0]; a0[3] += v * p23[1];
    a1[0] += v * p45[0]; a1[1] += v * p45[1];
    a1[2] += v * p67[0]; a1[3] += v * p67[1];
  }
  short8 ov;
#pragma unroll
  for (int e = 0; e < 4; ++e) {
    ov[e]     = (short)phi_enc(a0[e]);   // t2 = tanh(0.5*a) -> phi domain
    ov[e + 4] = (short)phi_enc(a1[e]);
  }
  *(short8*)(t2p + (size_t)h * BATCH + b) = ov;
}

// ---- sparse Wout apply: xp[n,b] = sum val*t3[col,b], t3 fp8 e4m3
__global__ __launch_bounds__(256) void sparse_wo(
    const uint8_t* __restrict__ t3f8,
    const unsigned* __restrict__ pack, const int* __restrict__ nnz,
    int rowoff, float* __restrict__ xp)
{
  const int nrow = blockIdx.x;
  const int b = threadIdx.x * 8;
  const int rg = rowoff + nrow;
  const unsigned* pr = pack + (size_t)rg * CAP;
  const int cnt = nnz[rg];
  f32x4 a0 = {0.f, 0.f, 0.f, 0.f};
  f32x4 a1 = {0.f, 0.f, 0.f, 0.f};
  int j = 0;
  for (; j + 4 <= cnt; j += 4) {
    const u32x4 w4 = *(const u32x4*)(pr + j);
    int2 t[4];
#pragma unroll
    for (int q = 0; q < 4; ++q)
      t[q] = *(const int2*)(t3f8 + (size_t)(w4[q] & 0xFFFFu) * BATCH + b);
#pragma unroll
    for (int q = 0; q < 4; ++q) {
      const float v = bf2f((short)(w4[q] >> 16));
      const f32x2 p01 = __builtin_amdgcn_cvt_pk_f32_fp8(t[q].x, false);
      const f32x2 p23 = __builtin_amdgcn_cvt_pk_f32_fp8(t[q].x, true);
      const f32x2 p45 = __builtin_amdgcn_cvt_pk_f32_fp8(t[q].y, false);
      const f32x2 p67 = __builtin_amdgcn_cvt_pk_f32_fp8(t[q].y, true);
      a0[0] += v * p01[0]; a0[1] += v * p01[1];
      a0[2] += v * p23[0]; a0[3] += v * p23[1];
      a1[0] += v * p45[0]; a1[1] += v * p45[1];
      a1[2] += v * p67[0]; a1[3] += v * p67[1];
    }
  }
  for (; j < cnt; ++j) {
    const unsigned pk = pr[j];
    const float v = bf2f((short)(pk >> 16));
    const int2 t = *(const int2*)(t3f8 + (size_t)(pk & 0xFFFFu) * BATCH + b);
    const f32x2 p01 = __builtin_amdgcn_cvt_pk_f32_fp8(t.x, false);
    const f32x2 p23 = __builtin_amdgcn_cvt_pk_f32_fp8(t.x, true);
    const f32x2 p45 = __builtin_amdgcn_cvt_pk_f32_fp8(t.y, false);
    const f32x2 p67 = __builtin_amdgcn_cvt_pk_f32_fp8(t.y, true);
    a0[0] += v * p01[0]; a0[1] += v * p01[1];
    a0[2] += v * p23[0]; a0[3] += v * p23[1];
    a1[0] += v * p45[0]; a1[1] += v * p45[1];
    a1[2] += v * p67[0]; a1[3] += v * p67[1];
  }
  float* orow = xp + (size_t)nrow * BATCH + b;
  *(f32x4*)orow = a0;
  *(f32x4*)(orow + 4) = a1;
}

// ---- fused epilogue: x_new = chS + xp^T; sigmoid->out, x f32, x bf16 (B,N), phi(x)->tfT (N,B)
__global__ __launch_bounds__(256) void fuse_out(
    const float* __restrict__ xpT,
    const float* __restrict__ chS,
    float* __restrict__ dout,
    float* __restrict__ xf,
    bf16* __restrict__ xb,
    unsigned short* __restrict__ tfT)
{
  __shared__ float lc[64][65];
  __shared__ float lx[64][65];
  const int n0 = blockIdx.x * 64, b0 = blockIdx.y * 64;
  const int tc = threadIdx.x & 63, tr = threadIdx.x >> 6;
#pragma unroll
  for (int i = 0; i < 16; ++i) {
    const int r = tr + i * 4;
    lc[r][tc] = chS[(size_t)(b0 + r) * NN + n0 + tc];
    lx[r][tc] = xpT[(size_t)(n0 + r) * BATCH + b0 + tc];
  }
  __syncthreads();
#pragma unroll
  for (int i = 0; i < 16; ++i) {
    const int r = tr + i * 4;
    const float v = lc[r][tc] + lx[tc][r];
    const size_t o = (size_t)(b0 + r) * NN + n0 + tc;
    dout[o] = 1.f / (1.f + expf(-v));
    xf[o] = v;
    xb[o] = __float2bfloat16(v);
  }
#pragma unroll
  for (int i = 0; i < 16; ++i) {
    const int r = tr + i * 4;
    const float v = lc[tc][r] + lx[r][tc];
    tfT[(size_t)(n0 + r) * BATCH + b0 + tc] = phi_enc(v);
  }
}

// ---- initial prep (k=0): from x (B,N) make xb (B,N) and phi(x)->tfT (N,B)
__global__ __launch_bounds__(256) void init_prep(
    const float* __restrict__ x, bf16* __restrict__ xb, unsigned short* __restrict__ tfT)
{
  __shared__ float ls[64][65];
  const int n0 = blockIdx.x * 64, b0 = blockIdx.y * 64;
  const int tc = threadIdx.x & 63, tr = threadIdx.x >> 6;
#pragma unroll
  for (int i = 0; i < 16; ++i) {
    const int r = tr + i * 4;
    const size_t o = (size_t)(b0 + r) * NN + n0 + tc;
    const float v = x[o];
    ls[r][tc] = v;
    xb[o] = __float2bfloat16(v);
  }
  __syncthreads();
#pragma unroll
  for (int i = 0; i < 16; ++i) {
    const int r = tr + i * 4;
    tfT[(size_t)(n0 + r) * BATCH + b0 + tc] = phi_enc(ls[tc][r]);
  }
}

extern "C" void kernel_launch(void* const* d_in, const int* in_sizes, int n_in,
                              void* d_out, int out_size, void* d_ws, size_t ws_size,
                              hipStream_t stream)
{
  const float* x_in  = (const float*)d_in[0];
  const float* S     = (const float*)d_in[1];
  const float* B1    = (const float*)d_in[2];
  const float* B2    = (const float*)d_in[3];
  const float* Wv1   = (const float*)d_in[4];
  const float* Wout1 = (const float*)d_in[5];
  const float* Wv2   = (const float*)d_in[6];
  const float* Wout2 = (const float*)d_in[7];
  const int* idx1f   = (const int*)d_in[8];
  const int* idx1m   = (const int*)d_in[9];
  const int* idx2f   = (const int*)d_in[10];
  const int* idx2m   = (const int*)d_in[11];
  float* out = (float*)d_out;

  uint8_t* p = (uint8_t*)d_ws;
  auto alloc = [&](size_t bytes) -> void* {
    void* r = p;
    p += (bytes + 255) & ~(size_t)255;
    return r;
  };
  bf16*  SmIT = (bf16*)alloc((size_t)10 * NN * NN * sizeof(bf16));
  bf16*  B1T  = (bf16*)alloc((size_t)H1C * NN * sizeof(bf16));
  bf16*  B2T  = (bf16*)alloc((size_t)H2C * NN * sizeof(bf16));
  unsigned* cpack = (unsigned*)alloc((size_t)ROWS_TOTAL * CAP * sizeof(unsigned));
  int*   cnnz  = (int*)alloc((size_t)ROWS_TOTAL * sizeof(int));
  float* xf   = (float*)alloc((size_t)BATCH * NN * sizeof(float));
  bf16*  xb   = (bf16*)alloc((size_t)BATCH * NN * sizeof(bf16));
  unsigned short* tfT = (unsigned short*)alloc((size_t)NN * BATCH * sizeof(unsigned short)); // phi(x)
  float* chS  = (float*)alloc((size_t)BATCH * NN * sizeof(float));
  bf16*  chSb = (bf16*)alloc((size_t)BATCH * NN * sizeof(bf16));
  uint8_t* t1f8 = (uint8_t*)alloc((size_t)H2C * BATCH);                                       // fp8 t1
  uint8_t* t3f8 = (uint8_t*)alloc((size_t)H2C * BATCH);                                       // fp8 t3
  unsigned short* zTb = (unsigned short*)alloc((size_t)H2C * BATCH * sizeof(unsigned short)); // bf16 z
  unsigned short* t2p = (unsigned short*)alloc((size_t)H2C * BATCH * sizeof(unsigned short)); // phi(t2)
  float* xpT  = (float*)alloc((size_t)NN * BATCH * sizeof(float));
  (void)ws_size; (void)in_sizes; (void)n_in; (void)out_size;

  // --- per-call prep
  prep_smit<<<dim3(NN / 64, NN / 64, 10), 256, 0, stream>>>(S, SmIT);
  prep_bt<<<dim3(H1C / 64, NN / 64), 256, 0, stream>>>(B1, B1T, H1C);
  prep_bt<<<dim3(H2C / 64, NN / 64), 256, 0, stream>>>(B2, B2T, H2C);
  csr_build<<<5 * H1C, 256, 0, stream>>>(Wv1,   H1C, cpack, cnnz, ROW_WV1);
  csr_build<<<5 * NN,  256, 0, stream>>>(Wout1, H1C, cpack, cnnz, ROW_WO1);
  csr_build<<<5 * H2C, 256, 0, stream>>>(Wv2,   H2C, cpack, cnnz, ROW_WV2);
  csr_build<<<5 * NN,  256, 0, stream>>>(Wout2, H2C, cpack, cnnz, ROW_WO2);
  init_prep<<<dim3(NN / 64, BATCH / 64), 256, 0, stream>>>(x_in, xb, tfT);

  for (int k = 0; k < 10; ++k) {
    const bool g1 = (k % 2 == 0);
    const int j = k / 2;
    const int H = g1 ? H1C : H2C;
    const bf16* BmT = g1 ? B1T : B2T;
    const int* idf = g1 ? idx1f : idx2f;
    const int* idm = g1 ? idx1m : idx2m;
    const int wv_off = g1 ? (ROW_WV1 + j * H1C) : (ROW_WV2 + j * H2C);
    const int wo_off = g1 ? (ROW_WO1 + j * NN)  : (ROW_WO2 + j * NN);
    const float* xcur = (k == 0) ? x_in : xf;
    const int gb = (BATCH / 128) * (H / 128);   // z-GEMM blocks (bn fast, 16 wide)

    // chS = x + x @ (S[k]-I)   (BM=64 variant: 256 blocks -> full CU coverage)
    gemm_bt64<<<dim3(NN / 128, BATCH / 64), 128, 0, stream>>>(
        xb, SmIT + (size_t)k * NN * NN, chS, chSb, xcur, BATCH, NN, NN);
    // merged: zTb = bf16(BmT @ chS^T)  ||  t1f8 = cn(tfT, idf)
    if (g1) zgemm_cn<6><<<gb + H, 256, 0, stream>>>(BmT, chSb, (bf16*)zTb, NN, gb, tfT, idf, t1f8);
    else    zgemm_cn<8><<<gb + H, 256, 0, stream>>>(BmT, chSb, (bf16*)zTb, NN, gb, tfT, idf, t1f8);
    // t2p = phi( z + Wv @ t1 )
    sparse_wv<<<dim3(H, 1), 256, 0, stream>>>(zTb, t1f8, cpack, cnnz, wv_off, t2p);
    // t3f8 = cn(t2p, idm)
    if (g1) cn_kernel<6><<<dim3(H, 1), 256, 0, stream>>>(t2p, idm, t3f8);
    else    cn_kernel<8><<<dim3(H, 1), 256, 0, stream>>>(t2p, idm, t3f8);
    // xpT = Wout @ t3
    sparse_wo<<<dim3(NN, 1), 256, 0, stream>>>(t3f8, cpack, cnnz, wo_off, xpT);
    // epilogue
    fuse_out<<<dim3(NN / 64, BATCH / 64), 256, 0, stream>>>(
        xpT, chS, out + (size_t)k * BATCH * NN, xf, xb, tfT);
  }
}

// Round 13
// 1487.441 us; speedup vs baseline: 1.9975x; 1.1036x over previous
//
#include <hip/hip_runtime.h>
#include <hip/hip_bf16.h>
#include <stdint.h>
#include <stddef.h>

using bf16 = __hip_bfloat16;
typedef __attribute__((ext_vector_type(8))) short short8;
typedef __attribute__((ext_vector_type(2))) float f32x2;
typedef __attribute__((ext_vector_type(4))) float f32x4;
typedef __attribute__((ext_vector_type(4))) unsigned u32x4;

constexpr int BATCH = 2048;
constexpr int NN    = 1024;
constexpr int H1C   = 3072;
constexpr int H2C   = 4096;
constexpr int CAP   = 128;   // max nnz per sparse row
constexpr int CHS_GB = (NN / 128) * (BATCH / 64);  // 256 chS-GEMM blocks

// CSR global row offsets
constexpr int ROW_WV1 = 0;                 // 5*3072 rows, len 3072
constexpr int ROW_WO1 = 5 * H1C;           // 5*1024 rows, len 3072
constexpr int ROW_WV2 = ROW_WO1 + 5 * NN;  // 5*4096 rows, len 4096
constexpr int ROW_WO2 = ROW_WV2 + 5 * H2C; // 5*1024 rows, len 4096
constexpr int ROWS_TOTAL = ROW_WO2 + 5 * NN; // 46080

__device__ __forceinline__ unsigned short f2bf(float f) {
  unsigned u = __float_as_uint(f);
  unsigned r = 0x7FFFu + ((u >> 16) & 1u);
  return (unsigned short)((u + r) >> 16);
}
__device__ __forceinline__ float bf2f(short s) {
  return __uint_as_float(((unsigned)(unsigned short)s) << 16);
}

// phi-domain encode of a pre-activation x (where t = tanh(x/2)):
//   value = sign(x) * phi(|x|),  phi(y) = log((1+e^-y)/(1-e^-y)) = -log(tanh(y/2))
//   x == 0  ->  +inf  (encodes t==0, excluded from products)
__device__ __forceinline__ unsigned short phi_enc(float x) {
  const float e = expf(-fabsf(x));
  const float phi = logf((1.f + e) / (1.f - e));  // +inf iff x==0
  return (unsigned short)(f2bf(phi) | (unsigned short)((__float_as_uint(x) >> 31) << 15));
}

__device__ __forceinline__ void gload16(const void* g, void* lds_base) {
  __builtin_amdgcn_global_load_lds(
      (const __attribute__((address_space(1))) void*)g,
      (__attribute__((address_space(3))) void*)lds_base, 16, 0, 0);
}

// ---- cn math body: given D phi-encoded short8 values, produce 8 signed LLR floats
template<int D>
__device__ __forceinline__ void cn_math(const short8* v, float* rs) {
  float s[8];
  unsigned sg[8];
  bool any[8];
#pragma unroll
  for (int e = 0; e < 8; ++e) { s[e] = 0.f; sg[e] = 0u; any[e] = false; }
#pragma unroll
  for (int d = 0; d < D; ++d) {
#pragma unroll
    for (int e = 0; e < 8; ++e) {
      const unsigned bits = (unsigned)(unsigned short)v[d][e];
      sg[e] ^= bits >> 15;
      const unsigned a = bits & 0x7FFFu;
      const bool nz = (a != 0x7F80u);   // +inf encodes t==0 (excluded)
      any[e] |= nz;
      s[e] += nz ? __uint_as_float(a << 16) : 0.f;
    }
  }
#pragma unroll
  for (int e = 0; e < 8; ++e) {
    const float y = fmaxf(s[e], 1.0000005e-6f);   // == clip(|u|, 0.999999)
    const float u = expf(-y);
    float r = logf((1.f + u) / (1.f - u));
    r = any[e] ? r : 0.f;
    rs[e] = __uint_as_float(__float_as_uint(r) | (sg[e] << 31));
  }
}

__device__ __forceinline__ void cn_store_fp8(const float* rs, uint8_t* dst) {
  int lo = 0, hi = 0;
  lo = __builtin_amdgcn_cvt_pk_fp8_f32(rs[0], rs[1], lo, false);
  lo = __builtin_amdgcn_cvt_pk_fp8_f32(rs[2], rs[3], lo, true);
  hi = __builtin_amdgcn_cvt_pk_fp8_f32(rs[4], rs[5], hi, false);
  hi = __builtin_amdgcn_cvt_pk_fp8_f32(rs[6], rs[7], hi, true);
  int2 o; o.x = lo; o.y = hi;
  *(int2*)dst = o;
}

// ---- merged L1: chS GEMM (blocks [0, CHS_GB)) + cn1 fp8 (blocks [CHS_GB, CHS_GB+H))
//      chS: BM=64 x BN=128, 4 waves of 64x32 each; chS = xb @ SmIT^T + xcur (f32 + bf16 out)
template<int D>
__global__ __launch_bounds__(256, 2) void chs_cn(
    const bf16* __restrict__ A, const bf16* __restrict__ BT,
    float* __restrict__ C, bf16* __restrict__ Cb, const float* __restrict__ add,
    const unsigned short* __restrict__ src, const int* __restrict__ idx,
    uint8_t* __restrict__ outf8)
{
  __shared__ bf16 As[64 * 32];
  __shared__ bf16 Bs[128 * 32];
  const int bid = blockIdx.x;
  const int tid = threadIdx.x;
  if (bid < CHS_GB) {
    const int lane = tid & 63;
    const int w    = tid >> 6;          // 0..3
    const int bn = bid & 7;             // NN/128 = 8
    const int bm = bid >> 3;            // BATCH/64 = 32
    const int wn = w * 32;
    const int l15 = lane & 15;
    const int lk  = (lane >> 4) * 8;
    const int ld4 = (lane >> 4) * 4;
    const int sr  = lane >> 2;
    const int kc  = (lane & 3) * 8;

    f32x4 acc[4][2];
#pragma unroll
    for (int i = 0; i < 4; ++i)
#pragma unroll
      for (int j = 0; j < 2; ++j)
#pragma unroll
        for (int e = 0; e < 4; ++e) acc[i][j][e] = 0.f;

    const size_t rA = (size_t)bm * 64;
    const size_t rB = (size_t)bn * 128;

    for (int kt = 0; kt < NN; kt += 32) {
#pragma unroll
      for (int c = 0; c < 3; ++c) {     // 12 slots (4 A + 8 B), 3 per wave
        const int slot = w * 3 + c;
        if (slot < 4) {
          const int r = slot * 16 + sr;
          gload16(A + (rA + r) * (size_t)NN + kt + kc, &As[slot * 512]);
        } else {
          const int r = (slot - 4) * 16 + sr;
          gload16(BT + (rB + r) * (size_t)NN + kt + kc, &Bs[(slot - 4) * 512]);
        }
      }
      __syncthreads();
      short8 af[4], bfr[2];
#pragma unroll
      for (int f = 0; f < 4; ++f)
        af[f] = *(const short8*)&As[(f * 16 + l15) * 32 + lk];
#pragma unroll
      for (int f = 0; f < 2; ++f)
        bfr[f] = *(const short8*)&Bs[(wn + f * 16 + l15) * 32 + lk];
#pragma unroll
      for (int i = 0; i < 4; ++i)
#pragma unroll
        for (int j = 0; j < 2; ++j)
          acc[i][j] = __builtin_amdgcn_mfma_f32_16x16x32_bf16(af[i], bfr[j], acc[i][j], 0, 0, 0);
      __syncthreads();
    }

#pragma unroll
    for (int i = 0; i < 4; ++i) {
      const int row0 = bm * 64 + i * 16 + ld4;
#pragma unroll
      for (int j = 0; j < 2; ++j) {
        const int col = bn * 128 + wn + j * 16 + l15;
#pragma unroll
        for (int e = 0; e < 4; ++e) {
          const size_t o = (size_t)(row0 + e) * NN + col;
          float v = acc[i][j][e] + add[o];
          C[o] = v;
          Cb[o] = __float2bfloat16(v);
        }
      }
    }
  } else {
    const int h = bid - CHS_GB;
    const int b = tid * 8;
    const int* ir = idx + (size_t)h * D;
    int rows[D];
#pragma unroll
    for (int d = 0; d < D; ++d) rows[d] = ir[d];
    short8 v[D];
#pragma unroll
    for (int d = 0; d < D; ++d)
      v[d] = *(const short8*)(src + (size_t)rows[d] * BATCH + b);
    float rs[8];
    cn_math<D>(v, rs);
    cn_store_fp8(rs, outf8 + (size_t)h * BATCH + b);
  }
}

// ---- merged L2: z-GEMM (blocks [0, gb)) + wv-gather (blocks [gb, gb+H))
//      GEMM: zTb[H,2048] = bf16( BmT @ chSb^T );  gather: gTb[h,:] = bf16( sum val*t1f8[col,:] )
__global__ __launch_bounds__(256, 2) void zgemm_wv(
    const bf16* __restrict__ A, const bf16* __restrict__ BT, bf16* __restrict__ Cb,
    int K, int gb,
    const uint8_t* __restrict__ t1f8,
    const unsigned* __restrict__ pack, const int* __restrict__ nnz,
    int rowoff, unsigned short* __restrict__ gTb)
{
  __shared__ bf16 As[128 * 32];
  __shared__ bf16 Bs[128 * 32];
  const int bid = blockIdx.x;
  if (bid < gb) {
    const int tid  = threadIdx.x;
    const int lane = tid & 63;
    const int w    = tid >> 6;
    const int bn = bid & 15;      // BATCH/128 = 16 tiles
    const int bm = bid >> 4;
    const int wm = (w >> 1) * 64, wn = (w & 1) * 64;
    const int l15 = lane & 15;
    const int lk  = (lane >> 4) * 8;
    const int ld4 = (lane >> 4) * 4;
    const int sr  = lane >> 2;
    const int kc  = (lane & 3) * 8;

    f32x4 acc[4][4];
#pragma unroll
    for (int i = 0; i < 4; ++i)
#pragma unroll
      for (int j = 0; j < 4; ++j)
#pragma unroll
        for (int e = 0; e < 4; ++e) acc[i][j][e] = 0.f;

    const size_t rA = (size_t)bm * 128;
    const size_t rB = (size_t)bn * 128;

    for (int kt = 0; kt < K; kt += 32) {
#pragma unroll
      for (int c = 0; c < 2; ++c) {
        const int slot = w * 2 + c;
        const int r = slot * 16 + sr;
        gload16(A  + (rA + r) * (size_t)K + kt + kc, &As[slot * 512]);
        gload16(BT + (rB + r) * (size_t)K + kt + kc, &Bs[slot * 512]);
      }
      __syncthreads();
      short8 af[4], bfr[4];
#pragma unroll
      for (int f = 0; f < 4; ++f) {
        af[f]  = *(const short8*)&As[(wm + f * 16 + l15) * 32 + lk];
        bfr[f] = *(const short8*)&Bs[(wn + f * 16 + l15) * 32 + lk];
      }
#pragma unroll
      for (int i = 0; i < 4; ++i)
#pragma unroll
        for (int j = 0; j < 4; ++j)
          acc[i][j] = __builtin_amdgcn_mfma_f32_16x16x32_bf16(af[i], bfr[j], acc[i][j], 0, 0, 0);
      __syncthreads();
    }

#pragma unroll
    for (int i = 0; i < 4; ++i) {
      const int row0 = bm * 128 + wm + i * 16 + ld4;
#pragma unroll
      for (int j = 0; j < 4; ++j) {
        const int col = bn * 128 + wn + j * 16 + l15;
#pragma unroll
        for (int e = 0; e < 4; ++e)
          Cb[(size_t)(row0 + e) * BATCH + col] = __float2bfloat16(acc[i][j][e]);
      }
    }
  } else {
    const int h = bid - gb;
    const int b = threadIdx.x * 8;
    const int rg = rowoff + h;
    const unsigned* pr = pack + (size_t)rg * CAP;
    const int n = nnz[rg];
    f32x4 a0 = {0.f, 0.f, 0.f, 0.f};
    f32x4 a1 = {0.f, 0.f, 0.f, 0.f};
    int j = 0;
    for (; j + 4 <= n; j += 4) {
      const u32x4 w4 = *(const u32x4*)(pr + j);
      int2 t[4];
#pragma unroll
      for (int q = 0; q < 4; ++q)
        t[q] = *(const int2*)(t1f8 + (size_t)(w4[q] & 0xFFFFu) * BATCH + b);
#pragma unroll
      for (int q = 0; q < 4; ++q) {
        const float v = bf2f((short)(w4[q] >> 16));
        const f32x2 p01 = __builtin_amdgcn_cvt_pk_f32_fp8(t[q].x, false);
        const f32x2 p23 = __builtin_amdgcn_cvt_pk_f32_fp8(t[q].x, true);
        const f32x2 p45 = __builtin_amdgcn_cvt_pk_f32_fp8(t[q].y, false);
        const f32x2 p67 = __builtin_amdgcn_cvt_pk_f32_fp8(t[q].y, true);
        a0[0] += v * p01[0]; a0[1] += v * p01[1];
        a0[2] += v * p23[0]; a0[3] += v * p23[1];
        a1[0] += v * p45[0]; a1[1] += v * p45[1];
        a1[2] += v * p67[0]; a1[3] += v * p67[1];
      }
    }
    for (; j < n; ++j) {
      const unsigned pk = pr[j];
      const float v = bf2f((short)(pk >> 16));
      const int2 t = *(const int2*)(t1f8 + (size_t)(pk & 0xFFFFu) * BATCH + b);
      const f32x2 p01 = __builtin_amdgcn_cvt_pk_f32_fp8(t.x, false);
      const f32x2 p23 = __builtin_amdgcn_cvt_pk_f32_fp8(t.x, true);
      const f32x2 p45 = __builtin_amdgcn_cvt_pk_f32_fp8(t.y, false);
      const f32x2 p67 = __builtin_amdgcn_cvt_pk_f32_fp8(t.y, true);
      a0[0] += v * p01[0]; a0[1] += v * p01[1];
      a0[2] += v * p23[0]; a0[3] += v * p23[1];
      a1[0] += v * p45[0]; a1[1] += v * p45[1];
      a1[2] += v * p67[0]; a1[3] += v * p67[1];
    }
    short8 ov;
#pragma unroll
    for (int e = 0; e < 4; ++e) {
      ov[e]     = (short)f2bf(a0[e]);
      ov[e + 4] = (short)f2bf(a1[e]);
    }
    *(short8*)(gTb + (size_t)h * BATCH + b) = ov;
  }
}

// ---- L3: t2p[h,b] = phi_enc( z[h,b] + g[h,b] )  (both bf16)
__global__ __launch_bounds__(256) void phi_add(
    const unsigned short* __restrict__ zb, const unsigned short* __restrict__ gbuf,
    unsigned short* __restrict__ t2p)
{
  const int h = blockIdx.x;
  const int b = threadIdx.x * 8;
  const short8 z = *(const short8*)(zb + (size_t)h * BATCH + b);
  const short8 g = *(const short8*)(gbuf + (size_t)h * BATCH + b);
  short8 ov;
#pragma unroll
  for (int e = 0; e < 8; ++e)
    ov[e] = (short)phi_enc(bf2f(z[e]) + bf2f(g[e]));
  *(short8*)(t2p + (size_t)h * BATCH + b) = ov;
}

// ---- prep: SmIT[k][n][m] = bf16(S[k][m][n] - (m==n))
__global__ __launch_bounds__(256) void prep_smit(const float* __restrict__ S, bf16* __restrict__ out)
{
  __shared__ float ls[64][65];
  const int k = blockIdx.z;
  const int n0 = blockIdx.x * 64, m0 = blockIdx.y * 64;
  const float* Sk = S + (size_t)k * NN * NN;
  bf16* ok = out + (size_t)k * NN * NN;
  const int tc = threadIdx.x & 63, tr = threadIdx.x >> 6;
#pragma unroll
  for (int i = 0; i < 16; ++i) {
    const int r = tr + i * 4;
    ls[r][tc] = Sk[(size_t)(m0 + r) * NN + n0 + tc];
  }
  __syncthreads();
#pragma unroll
  for (int i = 0; i < 16; ++i) {
    const int r = tr + i * 4;
    float v = ls[tc][r] - ((m0 + tc) == (n0 + r) ? 1.f : 0.f);
    ok[(size_t)(n0 + r) * NN + m0 + tc] = __float2bfloat16(v);
  }
}

// ---- prep: out[h][n] = bf16(Bsrc[n][h]);  Bsrc is (NN, H)
__global__ __launch_bounds__(256) void prep_bt(const float* __restrict__ Bsrc, bf16* __restrict__ out, int H)
{
  __shared__ float ls[64][65];
  const int h0 = blockIdx.x * 64, n0 = blockIdx.y * 64;
  const int tc = threadIdx.x & 63, tr = threadIdx.x >> 6;
#pragma unroll
  for (int i = 0; i < 16; ++i) {
    const int r = tr + i * 4;
    ls[r][tc] = Bsrc[(size_t)(n0 + r) * H + h0 + tc];
  }
  __syncthreads();
#pragma unroll
  for (int i = 0; i < 16; ++i) {
    const int r = tr + i * 4;
    out[(size_t)(h0 + r) * NN + n0 + tc] = __float2bfloat16(ls[tc][r]);
  }
}

// ---- CSR build, vectorized: one block per row, f32x4 loads (1024 cols/chunk),
//      deterministic column-order compaction via 4 ballots + wave prefix.
//      packed entry: u32 = bf16(val)<<16 | col
__global__ __launch_bounds__(256) void csr_build(
    const float* __restrict__ W, int rowlen,
    unsigned* __restrict__ pack, int* __restrict__ nnz, int row_off)
{
  const int row = blockIdx.x;
  const float* wr = W + (size_t)row * rowlen;
  const size_t base = (size_t)(row_off + row) * CAP;
  __shared__ int wtot[4];
  __shared__ int cbase;
  if (threadIdx.x == 0) cbase = 0;
  __syncthreads();
  const int lane = threadIdx.x & 63, wv = threadIdx.x >> 6;
  const unsigned long long lanemask = (1ull << lane) - 1ull;
  for (int c0 = 0; c0 < rowlen; c0 += 1024) {
    const int c = c0 + threadIdx.x * 4;
    const f32x4 v = *(const f32x4*)(wr + c);
    unsigned long long m[4];
#pragma unroll
    for (int e = 0; e < 4; ++e) m[e] = __ballot(v[e] != 0.f);
    int pre_lane = 0;
#pragma unroll
    for (int e = 0; e < 4; ++e) pre_lane += __popcll(m[e] & lanemask);
    if (lane == 0)
      wtot[wv] = __popcll(m[0]) + __popcll(m[1]) + __popcll(m[2]) + __popcll(m[3]);
    __syncthreads();
    int pre = cbase + pre_lane;
    for (int i = 0; i < wv; ++i) pre += wtot[i];
    int off = 0;
#pragma unroll
    for (int e = 0; e < 4; ++e) {
      if (v[e] != 0.f) {
        const int p = pre + off;
        if (p < CAP) pack[base + p] = ((unsigned)f2bf(v[e]) << 16) | (unsigned)(c + e);
        ++off;
      }
    }
    __syncthreads();
    if (threadIdx.x == 0) cbase += wtot[0] + wtot[1] + wtot[2] + wtot[3];
    __syncthreads();
  }
  if (threadIdx.x == 0) nnz[row_off + row] = (cbase < CAP ? cbase : CAP);
}

// ---- standalone cn (fp8 out) for the second cn stage
template<int D>
__global__ __launch_bounds__(256) void cn_kernel(
    const unsigned short* __restrict__ src,  // (rows, BATCH) bf16 phi-encoded
    const int* __restrict__ idx,
    uint8_t* __restrict__ out)               // (H, BATCH) fp8 LLR
{
  const int h = blockIdx.x;
  const int b = threadIdx.x * 8;
  const int* ir = idx + (size_t)h * D;
  int rows[D];
#pragma unroll
  for (int d = 0; d < D; ++d) rows[d] = ir[d];
  short8 v[D];
#pragma unroll
  for (int d = 0; d < D; ++d)
    v[d] = *(const short8*)(src + (size_t)rows[d] * BATCH + b);
  float rs[8];
  cn_math<D>(v, rs);
  cn_store_fp8(rs, out + (size_t)h * BATCH + b);
}

// ---- sparse Wout apply: xp[n,b] = sum val*t3[col,b], t3 fp8 e4m3
__global__ __launch_bounds__(256) void sparse_wo(
    const uint8_t* __restrict__ t3f8,
    const unsigned* __restrict__ pack, const int* __restrict__ nnz,
    int rowoff, float* __restrict__ xp)
{
  const int nrow = blockIdx.x;
  const int b = threadIdx.x * 8;
  const int rg = rowoff + nrow;
  const unsigned* pr = pack + (size_t)rg * CAP;
  const int cnt = nnz[rg];
  f32x4 a0 = {0.f, 0.f, 0.f, 0.f};
  f32x4 a1 = {0.f, 0.f, 0.f, 0.f};
  int j = 0;
  for (; j + 4 <= cnt; j += 4) {
    const u32x4 w4 = *(const u32x4*)(pr + j);
    int2 t[4];
#pragma unroll
    for (int q = 0; q < 4; ++q)
      t[q] = *(const int2*)(t3f8 + (size_t)(w4[q] & 0xFFFFu) * BATCH + b);
#pragma unroll
    for (int q = 0; q < 4; ++q) {
      const float v = bf2f((short)(w4[q] >> 16));
      const f32x2 p01 = __builtin_amdgcn_cvt_pk_f32_fp8(t[q].x, false);
      const f32x2 p23 = __builtin_amdgcn_cvt_pk_f32_fp8(t[q].x, true);
      const f32x2 p45 = __builtin_amdgcn_cvt_pk_f32_fp8(t[q].y, false);
      const f32x2 p67 = __builtin_amdgcn_cvt_pk_f32_fp8(t[q].y, true);
      a0[0] += v * p01[0]; a0[1] += v * p01[1];
      a0[2] += v * p23[0]; a0[3] += v * p23[1];
      a1[0] += v * p45[0]; a1[1] += v * p45[1];
      a1[2] += v * p67[0]; a1[3] += v * p67[1];
    }
  }
  for (; j < cnt; ++j) {
    const unsigned pk = pr[j];
    const float v = bf2f((short)(pk >> 16));
    const int2 t = *(const int2*)(t3f8 + (size_t)(pk & 0xFFFFu) * BATCH + b);
    const f32x2 p01 = __builtin_amdgcn_cvt_pk_f32_fp8(t.x, false);
    const f32x2 p23 = __builtin_amdgcn_cvt_pk_f32_fp8(t.x, true);
    const f32x2 p45 = __builtin_amdgcn_cvt_pk_f32_fp8(t.y, false);
    const f32x2 p67 = __builtin_amdgcn_cvt_pk_f32_fp8(t.y, true);
    a0[0] += v * p01[0]; a0[1] += v * p01[1];
    a0[2] += v * p23[0]; a0[3] += v * p23[1];
    a1[0] += v * p45[0]; a1[1] += v * p45[1];
    a1[2] += v * p67[0]; a1[3] += v * p67[1];
  }
  float* orow = xp + (size_t)nrow * BATCH + b;
  *(f32x4*)orow = a0;
  *(f32x4*)(orow + 4) = a1;
}

// ---- fused epilogue: x_new = chS + xp^T; sigmoid->out, x f32, x bf16 (B,N), phi(x)->tfT (N,B)
__global__ __launch_bounds__(256) void fuse_out(
    const float* __restrict__ xpT,
    const float* __restrict__ chS,
    float* __restrict__ dout,
    float* __restrict__ xf,
    bf16* __restrict__ xb,
    unsigned short* __restrict__ tfT)
{
  __shared__ float lc[64][65];
  __shared__ float lx[64][65];
  const int n0 = blockIdx.x * 64, b0 = blockIdx.y * 64;
  const int tc = threadIdx.x & 63, tr = threadIdx.x >> 6;
#pragma unroll
  for (int i = 0; i < 16; ++i) {
    const int r = tr + i * 4;
    lc[r][tc] = chS[(size_t)(b0 + r) * NN + n0 + tc];
    lx[r][tc] = xpT[(size_t)(n0 + r) * BATCH + b0 + tc];
  }
  __syncthreads();
#pragma unroll
  for (int i = 0; i < 16; ++i) {
    const int r = tr + i * 4;
    const float v = lc[r][tc] + lx[tc][r];
    const size_t o = (size_t)(b0 + r) * NN + n0 + tc;
    dout[o] = 1.f / (1.f + expf(-v));
    xf[o] = v;
    xb[o] = __float2bfloat16(v);
  }
#pragma unroll
  for (int i = 0; i < 16; ++i) {
    const int r = tr + i * 4;
    const float v = lc[tc][r] + lx[r][tc];
    tfT[(size_t)(n0 + r) * BATCH + b0 + tc] = phi_enc(v);
  }
}

// ---- initial prep (k=0): from x (B,N) make xb (B,N) and phi(x)->tfT (N,B)
__global__ __launch_bounds__(256) void init_prep(
    const float* __restrict__ x, bf16* __restrict__ xb, unsigned short* __restrict__ tfT)
{
  __shared__ float ls[64][65];
  const int n0 = blockIdx.x * 64, b0 = blockIdx.y * 64;
  const int tc = threadIdx.x & 63, tr = threadIdx.x >> 6;
#pragma unroll
  for (int i = 0; i < 16; ++i) {
    const int r = tr + i * 4;
    const size_t o = (size_t)(b0 + r) * NN + n0 + tc;
    const float v = x[o];
    ls[r][tc] = v;
    xb[o] = __float2bfloat16(v);
  }
  __syncthreads();
#pragma unroll
  for (int i = 0; i < 16; ++i) {
    const int r = tr + i * 4;
    tfT[(size_t)(n0 + r) * BATCH + b0 + tc] = phi_enc(ls[tc][r]);
  }
}

extern "C" void kernel_launch(void* const* d_in, const int* in_sizes, int n_in,
                              void* d_out, int out_size, void* d_ws, size_t ws_size,
                              hipStream_t stream)
{
  const float* x_in  = (const float*)d_in[0];
  const float* S     = (const float*)d_in[1];
  const float* B1    = (const float*)d_in[2];
  const float* B2    = (const float*)d_in[3];
  const float* Wv1   = (const float*)d_in[4];
  const float* Wout1 = (const float*)d_in[5];
  const float* Wv2   = (const float*)d_in[6];
  const float* Wout2 = (const float*)d_in[7];
  const int* idx1f   = (const int*)d_in[8];
  const int* idx1m   = (const int*)d_in[9];
  const int* idx2f   = (const int*)d_in[10];
  const int* idx2m   = (const int*)d_in[11];
  float* out = (float*)d_out;

  uint8_t* p = (uint8_t*)d_ws;
  auto alloc = [&](size_t bytes) -> void* {
    void* r = p;
    p += (bytes + 255) & ~(size_t)255;
    return r;
  };
  bf16*  SmIT = (bf16*)alloc((size_t)10 * NN * NN * sizeof(bf16));
  bf16*  B1T  = (bf16*)alloc((size_t)H1C * NN * sizeof(bf16));
  bf16*  B2T  = (bf16*)alloc((size_t)H2C * NN * sizeof(bf16));
  unsigned* cpack = (unsigned*)alloc((size_t)ROWS_TOTAL * CAP * sizeof(unsigned));
  int*   cnnz  = (int*)alloc((size_t)ROWS_TOTAL * sizeof(int));
  float* xf   = (float*)alloc((size_t)BATCH * NN * sizeof(float));
  bf16*  xb   = (bf16*)alloc((size_t)BATCH * NN * sizeof(bf16));
  unsigned short* tfT = (unsigned short*)alloc((size_t)NN * BATCH * sizeof(unsigned short)); // phi(x)
  float* chS  = (float*)alloc((size_t)BATCH * NN * sizeof(float));
  bf16*  chSb = (bf16*)alloc((size_t)BATCH * NN * sizeof(bf16));
  uint8_t* t1f8 = (uint8_t*)alloc((size_t)H2C * BATCH);                                       // fp8 t1
  uint8_t* t3f8 = (uint8_t*)alloc((size_t)H2C * BATCH);                                       // fp8 t3
  unsigned short* zTb = (unsigned short*)alloc((size_t)H2C * BATCH * sizeof(unsigned short)); // bf16 z
  unsigned short* gTb = (unsigned short*)alloc((size_t)H2C * BATCH * sizeof(unsigned short)); // bf16 g = Wv@t1
  unsigned short* t2p = (unsigned short*)alloc((size_t)H2C * BATCH * sizeof(unsigned short)); // phi(t2)
  float* xpT  = (float*)alloc((size_t)NN * BATCH * sizeof(float));
  (void)ws_size; (void)in_sizes; (void)n_in; (void)out_size;

  // --- per-call prep
  prep_smit<<<dim3(NN / 64, NN / 64, 10), 256, 0, stream>>>(S, SmIT);
  prep_bt<<<dim3(H1C / 64, NN / 64), 256, 0, stream>>>(B1, B1T, H1C);
  prep_bt<<<dim3(H2C / 64, NN / 64), 256, 0, stream>>>(B2, B2T, H2C);
  csr_build<<<5 * H1C, 256, 0, stream>>>(Wv1,   H1C, cpack, cnnz, ROW_WV1);
  csr_build<<<5 * NN,  256, 0, stream>>>(Wout1, H1C, cpack, cnnz, ROW_WO1);
  csr_build<<<5 * H2C, 256, 0, stream>>>(Wv2,   H2C, cpack, cnnz, ROW_WV2);
  csr_build<<<5 * NN,  256, 0, stream>>>(Wout2, H2C, cpack, cnnz, ROW_WO2);
  init_prep<<<dim3(NN / 64, BATCH / 64), 256, 0, stream>>>(x_in, xb, tfT);

  for (int k = 0; k < 10; ++k) {
    const bool g1 = (k % 2 == 0);
    const int j = k / 2;
    const int H = g1 ? H1C : H2C;
    const bf16* BmT = g1 ? B1T : B2T;
    const int* idf = g1 ? idx1f : idx2f;
    const int* idm = g1 ? idx1m : idx2m;
    const int wv_off = g1 ? (ROW_WV1 + j * H1C) : (ROW_WV2 + j * H2C);
    const int wo_off = g1 ? (ROW_WO1 + j * NN)  : (ROW_WO2 + j * NN);
    const float* xcur = (k == 0) ? x_in : xf;
    const int gb = (BATCH / 128) * (H / 128);   // z-GEMM blocks (bn fast, 16 wide)

    // L1: chS = x + x @ (S[k]-I)  ||  t1f8 = cn(tfT, idf)
    if (g1) chs_cn<6><<<CHS_GB + H, 256, 0, stream>>>(
        xb, SmIT + (size_t)k * NN * NN, chS, chSb, xcur, tfT, idf, t1f8);
    else    chs_cn<8><<<CHS_GB + H, 256, 0, stream>>>(
        xb, SmIT + (size_t)k * NN * NN, chS, chSb, xcur, tfT, idf, t1f8);
    // L2: zTb = bf16(BmT @ chS^T)  ||  gTb = bf16(Wv @ t1)
    zgemm_wv<<<gb + H, 256, 0, stream>>>(
        BmT, chSb, (bf16*)zTb, NN, gb, t1f8, cpack, cnnz, wv_off, gTb);
    // L3: t2p = phi( z + g )
    phi_add<<<H, 256, 0, stream>>>(zTb, gTb, t2p);
    // L4: t3f8 = cn(t2p, idm)
    if (g1) cn_kernel<6><<<dim3(H, 1), 256, 0, stream>>>(t2p, idm, t3f8);
    else    cn_kernel<8><<<dim3(H, 1), 256, 0, stream>>>(t2p, idm, t3f8);
    // L5: xpT = Wout @ t3
    sparse_wo<<<dim3(NN, 1), 256, 0, stream>>>(t3f8, cpack, cnnz, wo_off, xpT);
    // L6: epilogue
    fuse_out<<<dim3(NN / 64, BATCH / 64), 256, 0, stream>>>(
        xpT, chS, out + (size_t)k * BATCH * NN, xf, xb, tfT);
  }
}

// Round 14
// 1455.663 us; speedup vs baseline: 2.0411x; 1.0218x over previous
//
#include <hip/hip_runtime.h>
#include <hip/hip_bf16.h>
#include <stdint.h>
#include <stddef.h>

using bf16 = __hip_bfloat16;
typedef __attribute__((ext_vector_type(8))) short short8;
typedef __attribute__((ext_vector_type(2))) float f32x2;
typedef __attribute__((ext_vector_type(4))) float f32x4;
typedef __attribute__((ext_vector_type(4))) unsigned u32x4;

constexpr int BATCH = 2048;
constexpr int NN    = 1024;
constexpr int H1C   = 3072;
constexpr int H2C   = 4096;
constexpr int CAP   = 128;   // max nnz per sparse row
constexpr int CHS_GB = (NN / 128) * (BATCH / 64);  // 256 chS-GEMM blocks
constexpr int NPAN  = 8;     // batch panels; blockIdx.x = panel -> XCD pin (bid%8)
constexpr int PW    = BATCH / NPAN;  // 256

// CSR global row offsets
constexpr int ROW_WV1 = 0;                 // 5*3072 rows, len 3072
constexpr int ROW_WO1 = 5 * H1C;           // 5*1024 rows, len 3072
constexpr int ROW_WV2 = ROW_WO1 + 5 * NN;  // 5*4096 rows, len 4096
constexpr int ROW_WO2 = ROW_WV2 + 5 * H2C; // 5*1024 rows, len 4096
constexpr int ROWS_TOTAL = ROW_WO2 + 5 * NN; // 46080

__device__ __forceinline__ unsigned short f2bf(float f) {
  unsigned u = __float_as_uint(f);
  unsigned r = 0x7FFFu + ((u >> 16) & 1u);
  return (unsigned short)((u + r) >> 16);
}
__device__ __forceinline__ float bf2f(short s) {
  return __uint_as_float(((unsigned)(unsigned short)s) << 16);
}

// phi-domain encode of a pre-activation x (where t = tanh(x/2)):
//   value = sign(x) * phi(|x|),  phi(y) = log((1+e^-y)/(1-e^-y)) = -log(tanh(y/2))
//   x == 0  ->  +inf  (encodes t==0, excluded from products)
__device__ __forceinline__ unsigned short phi_enc(float x) {
  const float e = expf(-fabsf(x));
  const float phi = logf((1.f + e) / (1.f - e));  // +inf iff x==0
  return (unsigned short)(f2bf(phi) | (unsigned short)((__float_as_uint(x) >> 31) << 15));
}

__device__ __forceinline__ void gload16(const void* g, void* lds_base) {
  __builtin_amdgcn_global_load_lds(
      (const __attribute__((address_space(1))) void*)g,
      (__attribute__((address_space(3))) void*)lds_base, 16, 0, 0);
}

// ---- cn math body: given D phi-encoded short8 values, produce 8 signed LLR floats
template<int D>
__device__ __forceinline__ void cn_math(const short8* v, float* rs) {
  float s[8];
  unsigned sg[8];
  bool any[8];
#pragma unroll
  for (int e = 0; e < 8; ++e) { s[e] = 0.f; sg[e] = 0u; any[e] = false; }
#pragma unroll
  for (int d = 0; d < D; ++d) {
#pragma unroll
    for (int e = 0; e < 8; ++e) {
      const unsigned bits = (unsigned)(unsigned short)v[d][e];
      sg[e] ^= bits >> 15;
      const unsigned a = bits & 0x7FFFu;
      const bool nz = (a != 0x7F80u);   // +inf encodes t==0 (excluded)
      any[e] |= nz;
      s[e] += nz ? __uint_as_float(a << 16) : 0.f;
    }
  }
#pragma unroll
  for (int e = 0; e < 8; ++e) {
    const float y = fmaxf(s[e], 1.0000005e-6f);   // == clip(|u|, 0.999999)
    const float u = expf(-y);
    float r = logf((1.f + u) / (1.f - u));
    r = any[e] ? r : 0.f;
    rs[e] = __uint_as_float(__float_as_uint(r) | (sg[e] << 31));
  }
}

__device__ __forceinline__ void cn_store_fp8(const float* rs, uint8_t* dst) {
  int lo = 0, hi = 0;
  lo = __builtin_amdgcn_cvt_pk_fp8_f32(rs[0], rs[1], lo, false);
  lo = __builtin_amdgcn_cvt_pk_fp8_f32(rs[2], rs[3], lo, true);
  hi = __builtin_amdgcn_cvt_pk_fp8_f32(rs[4], rs[5], hi, false);
  hi = __builtin_amdgcn_cvt_pk_fp8_f32(rs[6], rs[7], hi, true);
  int2 o; o.x = lo; o.y = hi;
  *(int2*)dst = o;
}

// ---- merged L1: chS GEMM (blocks [0, CHS_GB)) + cn1 fp8 (blocks [CHS_GB, CHS_GB+H))
//      chS: BM=64 x BN=128, 4 waves of 64x32 each; chS = xb @ SmIT^T + xcur (f32 + bf16 out)
template<int D>
__global__ __launch_bounds__(256, 2) void chs_cn(
    const bf16* __restrict__ A, const bf16* __restrict__ BT,
    float* __restrict__ C, bf16* __restrict__ Cb, const float* __restrict__ add,
    const unsigned short* __restrict__ src, const int* __restrict__ idx,
    uint8_t* __restrict__ outf8)
{
  __shared__ bf16 As[64 * 32];
  __shared__ bf16 Bs[128 * 32];
  const int bid = blockIdx.x;
  const int tid = threadIdx.x;
  if (bid < CHS_GB) {
    const int lane = tid & 63;
    const int w    = tid >> 6;          // 0..3
    const int bn = bid & 7;             // NN/128 = 8
    const int bm = bid >> 3;            // BATCH/64 = 32
    const int wn = w * 32;
    const int l15 = lane & 15;
    const int lk  = (lane >> 4) * 8;
    const int ld4 = (lane >> 4) * 4;
    const int sr  = lane >> 2;
    const int kc  = (lane & 3) * 8;

    f32x4 acc[4][2];
#pragma unroll
    for (int i = 0; i < 4; ++i)
#pragma unroll
      for (int j = 0; j < 2; ++j)
#pragma unroll
        for (int e = 0; e < 4; ++e) acc[i][j][e] = 0.f;

    const size_t rA = (size_t)bm * 64;
    const size_t rB = (size_t)bn * 128;

    for (int kt = 0; kt < NN; kt += 32) {
#pragma unroll
      for (int c = 0; c < 3; ++c) {     // 12 slots (4 A + 8 B), 3 per wave
        const int slot = w * 3 + c;
        if (slot < 4) {
          const int r = slot * 16 + sr;
          gload16(A + (rA + r) * (size_t)NN + kt + kc, &As[slot * 512]);
        } else {
          const int r = (slot - 4) * 16 + sr;
          gload16(BT + (rB + r) * (size_t)NN + kt + kc, &Bs[(slot - 4) * 512]);
        }
      }
      __syncthreads();
      short8 af[4], bfr[2];
#pragma unroll
      for (int f = 0; f < 4; ++f)
        af[f] = *(const short8*)&As[(f * 16 + l15) * 32 + lk];
#pragma unroll
      for (int f = 0; f < 2; ++f)
        bfr[f] = *(const short8*)&Bs[(wn + f * 16 + l15) * 32 + lk];
#pragma unroll
      for (int i = 0; i < 4; ++i)
#pragma unroll
        for (int j = 0; j < 2; ++j)
          acc[i][j] = __builtin_amdgcn_mfma_f32_16x16x32_bf16(af[i], bfr[j], acc[i][j], 0, 0, 0);
      __syncthreads();
    }

#pragma unroll
    for (int i = 0; i < 4; ++i) {
      const int row0 = bm * 64 + i * 16 + ld4;
#pragma unroll
      for (int j = 0; j < 2; ++j) {
        const int col = bn * 128 + wn + j * 16 + l15;
#pragma unroll
        for (int e = 0; e < 4; ++e) {
          const size_t o = (size_t)(row0 + e) * NN + col;
          float v = acc[i][j][e] + add[o];
          C[o] = v;
          Cb[o] = __float2bfloat16(v);
        }
      }
    }
  } else {
    const int h = bid - CHS_GB;
    const int b = tid * 8;
    const int* ir = idx + (size_t)h * D;
    int rows[D];
#pragma unroll
    for (int d = 0; d < D; ++d) rows[d] = ir[d];
    short8 v[D];
#pragma unroll
    for (int d = 0; d < D; ++d)
      v[d] = *(const short8*)(src + (size_t)rows[d] * BATCH + b);
    float rs[8];
    cn_math<D>(v, rs);
    cn_store_fp8(rs, outf8 + (size_t)h * BATCH + b);
  }
}

// ---- merged L2: z-GEMM (blocks [0, gb)) + wv-gather (blocks [gb, gb+H))
//      GEMM: zTb[H,2048] = bf16( BmT @ chSb^T );  gather: gTb[h,:] = bf16( sum val*t1f8[col,:] )
__global__ __launch_bounds__(256, 2) void zgemm_wv(
    const bf16* __restrict__ A, const bf16* __restrict__ BT, bf16* __restrict__ Cb,
    int K, int gb,
    const uint8_t* __restrict__ t1f8,
    const unsigned* __restrict__ pack, const int* __restrict__ nnz,
    int rowoff, unsigned short* __restrict__ gTb)
{
  __shared__ bf16 As[128 * 32];
  __shared__ bf16 Bs[128 * 32];
  const int bid = blockIdx.x;
  if (bid < gb) {
    const int tid  = threadIdx.x;
    const int lane = tid & 63;
    const int w    = tid >> 6;
    const int bn = bid & 15;      // BATCH/128 = 16 tiles
    const int bm = bid >> 4;
    const int wm = (w >> 1) * 64, wn = (w & 1) * 64;
    const int l15 = lane & 15;
    const int lk  = (lane >> 4) * 8;
    const int ld4 = (lane >> 4) * 4;
    const int sr  = lane >> 2;
    const int kc  = (lane & 3) * 8;

    f32x4 acc[4][4];
#pragma unroll
    for (int i = 0; i < 4; ++i)
#pragma unroll
      for (int j = 0; j < 4; ++j)
#pragma unroll
        for (int e = 0; e < 4; ++e) acc[i][j][e] = 0.f;

    const size_t rA = (size_t)bm * 128;
    const size_t rB = (size_t)bn * 128;

    for (int kt = 0; kt < K; kt += 32) {
#pragma unroll
      for (int c = 0; c < 2; ++c) {
        const int slot = w * 2 + c;
        const int r = slot * 16 + sr;
        gload16(A  + (rA + r) * (size_t)K + kt + kc, &As[slot * 512]);
        gload16(BT + (rB + r) * (size_t)K + kt + kc, &Bs[slot * 512]);
      }
      __syncthreads();
      short8 af[4], bfr[4];
#pragma unroll
      for (int f = 0; f < 4; ++f) {
        af[f]  = *(const short8*)&As[(wm + f * 16 + l15) * 32 + lk];
        bfr[f] = *(const short8*)&Bs[(wn + f * 16 + l15) * 32 + lk];
      }
#pragma unroll
      for (int i = 0; i < 4; ++i)
#pragma unroll
        for (int j = 0; j < 4; ++j)
          acc[i][j] = __builtin_amdgcn_mfma_f32_16x16x32_bf16(af[i], bfr[j], acc[i][j], 0, 0, 0);
      __syncthreads();
    }

#pragma unroll
    for (int i = 0; i < 4; ++i) {
      const int row0 = bm * 128 + wm + i * 16 + ld4;
#pragma unroll
      for (int j = 0; j < 4; ++j) {
        const int col = bn * 128 + wn + j * 16 + l15;
#pragma unroll
        for (int e = 0; e < 4; ++e)
          Cb[(size_t)(row0 + e) * BATCH + col] = __float2bfloat16(acc[i][j][e]);
      }
    }
  } else {
    const int h = bid - gb;
    const int b = threadIdx.x * 8;
    const int rg = rowoff + h;
    const unsigned* pr = pack + (size_t)rg * CAP;
    const int n = nnz[rg];
    f32x4 a0 = {0.f, 0.f, 0.f, 0.f};
    f32x4 a1 = {0.f, 0.f, 0.f, 0.f};
    int j = 0;
    for (; j + 4 <= n; j += 4) {
      const u32x4 w4 = *(const u32x4*)(pr + j);
      int2 t[4];
#pragma unroll
      for (int q = 0; q < 4; ++q)
        t[q] = *(const int2*)(t1f8 + (size_t)(w4[q] & 0xFFFFu) * BATCH + b);
#pragma unroll
      for (int q = 0; q < 4; ++q) {
        const float v = bf2f((short)(w4[q] >> 16));
        const f32x2 p01 = __builtin_amdgcn_cvt_pk_f32_fp8(t[q].x, false);
        const f32x2 p23 = __builtin_amdgcn_cvt_pk_f32_fp8(t[q].x, true);
        const f32x2 p45 = __builtin_amdgcn_cvt_pk_f32_fp8(t[q].y, false);
        const f32x2 p67 = __builtin_amdgcn_cvt_pk_f32_fp8(t[q].y, true);
        a0[0] += v * p01[0]; a0[1] += v * p01[1];
        a0[2] += v * p23[0]; a0[3] += v * p23[1];
        a1[0] += v * p45[0]; a1[1] += v * p45[1];
        a1[2] += v * p67[0]; a1[3] += v * p67[1];
      }
    }
    for (; j < n; ++j) {
      const unsigned pk = pr[j];
      const float v = bf2f((short)(pk >> 16));
      const int2 t = *(const int2*)(t1f8 + (size_t)(pk & 0xFFFFu) * BATCH + b);
      const f32x2 p01 = __builtin_amdgcn_cvt_pk_f32_fp8(t.x, false);
      const f32x2 p23 = __builtin_amdgcn_cvt_pk_f32_fp8(t.x, true);
      const f32x2 p45 = __builtin_amdgcn_cvt_pk_f32_fp8(t.y, false);
      const f32x2 p67 = __builtin_amdgcn_cvt_pk_f32_fp8(t.y, true);
      a0[0] += v * p01[0]; a0[1] += v * p01[1];
      a0[2] += v * p23[0]; a0[3] += v * p23[1];
      a1[0] += v * p45[0]; a1[1] += v * p45[1];
      a1[2] += v * p67[0]; a1[3] += v * p67[1];
    }
    short8 ov;
#pragma unroll
    for (int e = 0; e < 4; ++e) {
      ov[e]     = (short)f2bf(a0[e]);
      ov[e + 4] = (short)f2bf(a1[e]);
    }
    *(short8*)(gTb + (size_t)h * BATCH + b) = ov;
  }
}

// ---- L3 (panel-pinned): t2p[h,b] = phi_enc( z[h,b] + g[h,b] )  (both bf16)
//      blockIdx.x = panel (XCD pin), 4 h/block, lanes cover 256-col panel x4.
__global__ __launch_bounds__(256) void phi_add_pin(
    const unsigned short* __restrict__ zb, const unsigned short* __restrict__ gbuf,
    unsigned short* __restrict__ t2p)
{
  const int panel = blockIdx.x;
  const int w = threadIdx.x >> 6, lane = threadIdx.x & 63;
  const int h = blockIdx.y * 4 + w;
  const int b = panel * PW + lane * 4;
  const size_t o = (size_t)h * BATCH + b;
  const int2 z = *(const int2*)(zb + o);
  const int2 g = *(const int2*)(gbuf + o);
  const unsigned zx = (unsigned)z.x, zy = (unsigned)z.y;
  const unsigned gx = (unsigned)g.x, gy = (unsigned)g.y;
  unsigned short ov[4];
  ov[0] = phi_enc(bf2f((short)(zx & 0xFFFFu)) + bf2f((short)(gx & 0xFFFFu)));
  ov[1] = phi_enc(bf2f((short)(zx >> 16))    + bf2f((short)(gx >> 16)));
  ov[2] = phi_enc(bf2f((short)(zy & 0xFFFFu)) + bf2f((short)(gy & 0xFFFFu)));
  ov[3] = phi_enc(bf2f((short)(zy >> 16))    + bf2f((short)(gy >> 16)));
  int2 r;
  r.x = (int)((unsigned)ov[0] | ((unsigned)ov[1] << 16));
  r.y = (int)((unsigned)ov[2] | ((unsigned)ov[3] << 16));
  *(int2*)(t2p + o) = r;
}

// ---- L4 (panel-pinned): cn2 fp8 out; gathers t2p cols within own panel (L2-local)
template<int D>
__global__ __launch_bounds__(256) void cn_pin(
    const unsigned short* __restrict__ src,  // (rows, BATCH) bf16 phi-encoded
    const int* __restrict__ idx,
    uint8_t* __restrict__ out)               // (H, BATCH) fp8 LLR
{
  const int panel = blockIdx.x;
  const int w = threadIdx.x >> 6, lane = threadIdx.x & 63;
  const int h = blockIdx.y * 4 + w;
  const int b = panel * PW + lane * 4;
  const int* ir = idx + (size_t)h * D;
  int rows[D];
#pragma unroll
  for (int d = 0; d < D; ++d) rows[d] = ir[d];
  int2 v[D];
#pragma unroll
  for (int d = 0; d < D; ++d)
    v[d] = *(const int2*)(src + (size_t)rows[d] * BATCH + b);
  float s[4];
  unsigned sg[4];
  bool any[4];
#pragma unroll
  for (int e = 0; e < 4; ++e) { s[e] = 0.f; sg[e] = 0u; any[e] = false; }
#pragma unroll
  for (int d = 0; d < D; ++d) {
    const unsigned bx = (unsigned)v[d].x, by = (unsigned)v[d].y;
    const unsigned bits4[4] = { bx & 0xFFFFu, bx >> 16, by & 0xFFFFu, by >> 16 };
#pragma unroll
    for (int e = 0; e < 4; ++e) {
      sg[e] ^= bits4[e] >> 15;
      const unsigned a = bits4[e] & 0x7FFFu;
      const bool nz = (a != 0x7F80u);
      any[e] |= nz;
      s[e] += nz ? __uint_as_float(a << 16) : 0.f;
    }
  }
  float rs[4];
#pragma unroll
  for (int e = 0; e < 4; ++e) {
    const float y = fmaxf(s[e], 1.0000005e-6f);
    const float u = expf(-y);
    float r = logf((1.f + u) / (1.f - u));
    r = any[e] ? r : 0.f;
    rs[e] = __uint_as_float(__float_as_uint(r) | (sg[e] << 31));
  }
  int o = 0;
  o = __builtin_amdgcn_cvt_pk_fp8_f32(rs[0], rs[1], o, false);
  o = __builtin_amdgcn_cvt_pk_fp8_f32(rs[2], rs[3], o, true);
  *(int*)(out + (size_t)h * BATCH + b) = o;
}

// ---- L5 (panel-pinned): xp[n,b] = sum val*t3[col,b], t3 fp8; gathers within own panel
__global__ __launch_bounds__(256) void wo_pin(
    const uint8_t* __restrict__ t3f8,
    const unsigned* __restrict__ pack, const int* __restrict__ nnz,
    int rowoff, float* __restrict__ xp)
{
  const int panel = blockIdx.x;
  const int w = threadIdx.x >> 6, lane = threadIdx.x & 63;
  const int nrow = blockIdx.y * 4 + w;
  const int b = panel * PW + lane * 4;
  const int rg = rowoff + nrow;
  const unsigned* pr = pack + (size_t)rg * CAP;
  const int cnt = nnz[rg];
  f32x4 a = {0.f, 0.f, 0.f, 0.f};
  int j = 0;
  for (; j + 4 <= cnt; j += 4) {
    const u32x4 w4 = *(const u32x4*)(pr + j);
    unsigned t[4];
#pragma unroll
    for (int q = 0; q < 4; ++q)
      t[q] = *(const unsigned*)(t3f8 + (size_t)(w4[q] & 0xFFFFu) * BATCH + b);
#pragma unroll
    for (int q = 0; q < 4; ++q) {
      const float v = bf2f((short)(w4[q] >> 16));
      const f32x2 p01 = __builtin_amdgcn_cvt_pk_f32_fp8((int)t[q], false);
      const f32x2 p23 = __builtin_amdgcn_cvt_pk_f32_fp8((int)t[q], true);
      a[0] += v * p01[0]; a[1] += v * p01[1];
      a[2] += v * p23[0]; a[3] += v * p23[1];
    }
  }
  for (; j < cnt; ++j) {
    const unsigned pk = pr[j];
    const float v = bf2f((short)(pk >> 16));
    const unsigned t = *(const unsigned*)(t3f8 + (size_t)(pk & 0xFFFFu) * BATCH + b);
    const f32x2 p01 = __builtin_amdgcn_cvt_pk_f32_fp8((int)t, false);
    const f32x2 p23 = __builtin_amdgcn_cvt_pk_f32_fp8((int)t, true);
    a[0] += v * p01[0]; a[1] += v * p01[1];
    a[2] += v * p23[0]; a[3] += v * p23[1];
  }
  *(f32x4*)(xp + (size_t)nrow * BATCH + b) = a;
}

// ---- prep: SmIT[k][n][m] = bf16(S[k][m][n] - (m==n))
__global__ __launch_bounds__(256) void prep_smit(const float* __restrict__ S, bf16* __restrict__ out)
{
  __shared__ float ls[64][65];
  const int k = blockIdx.z;
  const int n0 = blockIdx.x * 64, m0 = blockIdx.y * 64;
  const float* Sk = S + (size_t)k * NN * NN;
  bf16* ok = out + (size_t)k * NN * NN;
  const int tc = threadIdx.x & 63, tr = threadIdx.x >> 6;
#pragma unroll
  for (int i = 0; i < 16; ++i) {
    const int r = tr + i * 4;
    ls[r][tc] = Sk[(size_t)(m0 + r) * NN + n0 + tc];
  }
  __syncthreads();
#pragma unroll
  for (int i = 0; i < 16; ++i) {
    const int r = tr + i * 4;
    float v = ls[tc][r] - ((m0 + tc) == (n0 + r) ? 1.f : 0.f);
    ok[(size_t)(n0 + r) * NN + m0 + tc] = __float2bfloat16(v);
  }
}

// ---- prep: out[h][n] = bf16(Bsrc[n][h]);  Bsrc is (NN, H)
__global__ __launch_bounds__(256) void prep_bt(const float* __restrict__ Bsrc, bf16* __restrict__ out, int H)
{
  __shared__ float ls[64][65];
  const int h0 = blockIdx.x * 64, n0 = blockIdx.y * 64;
  const int tc = threadIdx.x & 63, tr = threadIdx.x >> 6;
#pragma unroll
  for (int i = 0; i < 16; ++i) {
    const int r = tr + i * 4;
    ls[r][tc] = Bsrc[(size_t)(n0 + r) * H + h0 + tc];
  }
  __syncthreads();
#pragma unroll
  for (int i = 0; i < 16; ++i) {
    const int r = tr + i * 4;
    out[(size_t)(h0 + r) * NN + n0 + tc] = __float2bfloat16(ls[tc][r]);
  }
}

// ---- CSR build, vectorized: one block per row, f32x4 loads (1024 cols/chunk),
//      deterministic column-order compaction via 4 ballots + wave prefix.
//      packed entry: u32 = bf16(val)<<16 | col
__global__ __launch_bounds__(256) void csr_build(
    const float* __restrict__ W, int rowlen,
    unsigned* __restrict__ pack, int* __restrict__ nnz, int row_off)
{
  const int row = blockIdx.x;
  const float* wr = W + (size_t)row * rowlen;
  const size_t base = (size_t)(row_off + row) * CAP;
  __shared__ int wtot[4];
  __shared__ int cbase;
  if (threadIdx.x == 0) cbase = 0;
  __syncthreads();
  const int lane = threadIdx.x & 63, wv = threadIdx.x >> 6;
  const unsigned long long lanemask = (1ull << lane) - 1ull;
  for (int c0 = 0; c0 < rowlen; c0 += 1024) {
    const int c = c0 + threadIdx.x * 4;
    const f32x4 v = *(const f32x4*)(wr + c);
    unsigned long long m[4];
#pragma unroll
    for (int e = 0; e < 4; ++e) m[e] = __ballot(v[e] != 0.f);
    int pre_lane = 0;
#pragma unroll
    for (int e = 0; e < 4; ++e) pre_lane += __popcll(m[e] & lanemask);
    if (lane == 0)
      wtot[wv] = __popcll(m[0]) + __popcll(m[1]) + __popcll(m[2]) + __popcll(m[3]);
    __syncthreads();
    int pre = cbase + pre_lane;
    for (int i = 0; i < wv; ++i) pre += wtot[i];
    int off = 0;
#pragma unroll
    for (int e = 0; e < 4; ++e) {
      if (v[e] != 0.f) {
        const int p = pre + off;
        if (p < CAP) pack[base + p] = ((unsigned)f2bf(v[e]) << 16) | (unsigned)(c + e);
        ++off;
      }
    }
    __syncthreads();
    if (threadIdx.x == 0) cbase += wtot[0] + wtot[1] + wtot[2] + wtot[3];
    __syncthreads();
  }
  if (threadIdx.x == 0) nnz[row_off + row] = (cbase < CAP ? cbase : CAP);
}

// ---- fused epilogue: x_new = chS + xp^T; sigmoid->out, x f32, x bf16 (B,N), phi(x)->tfT (N,B)
__global__ __launch_bounds__(256) void fuse_out(
    const float* __restrict__ xpT,
    const float* __restrict__ chS,
    float* __restrict__ dout,
    float* __restrict__ xf,
    bf16* __restrict__ xb,
    unsigned short* __restrict__ tfT)
{
  __shared__ float lc[64][65];
  __shared__ float lx[64][65];
  const int n0 = blockIdx.x * 64, b0 = blockIdx.y * 64;
  const int tc = threadIdx.x & 63, tr = threadIdx.x >> 6;
#pragma unroll
  for (int i = 0; i < 16; ++i) {
    const int r = tr + i * 4;
    lc[r][tc] = chS[(size_t)(b0 + r) * NN + n0 + tc];
    lx[r][tc] = xpT[(size_t)(n0 + r) * BATCH + b0 + tc];
  }
  __syncthreads();
#pragma unroll
  for (int i = 0; i < 16; ++i) {
    const int r = tr + i * 4;
    const float v = lc[r][tc] + lx[tc][r];
    const size_t o = (size_t)(b0 + r) * NN + n0 + tc;
    dout[o] = 1.f / (1.f + expf(-v));
    xf[o] = v;
    xb[o] = __float2bfloat16(v);
  }
#pragma unroll
  for (int i = 0; i < 16; ++i) {
    const int r = tr + i * 4;
    const float v = lc[tc][r] + lx[r][tc];
    tfT[(size_t)(n0 + r) * BATCH + b0 + tc] = phi_enc(v);
  }
}

// ---- initial prep (k=0): from x (B,N) make xb (B,N) and phi(x)->tfT (N,B)
__global__ __launch_bounds__(256) void init_prep(
    const float* __restrict__ x, bf16* __restrict__ xb, unsigned short* __restrict__ tfT)
{
  __shared__ float ls[64][65];
  const int n0 = blockIdx.x * 64, b0 = blockIdx.y * 64;
  const int tc = threadIdx.x & 63, tr = threadIdx.x >> 6;
#pragma unroll
  for (int i = 0; i < 16; ++i) {
    const int r = tr + i * 4;
    const size_t o = (size_t)(b0 + r) * NN + n0 + tc;
    const float v = x[o];
    ls[r][tc] = v;
    xb[o] = __float2bfloat16(v);
  }
  __syncthreads();
#pragma unroll
  for (int i = 0; i < 16; ++i) {
    const int r = tr + i * 4;
    tfT[(size_t)(n0 + r) * BATCH + b0 + tc] = phi_enc(ls[tc][r]);
  }
}

extern "C" void kernel_launch(void* const* d_in, const int* in_sizes, int n_in,
                              void* d_out, int out_size, void* d_ws, size_t ws_size,
                              hipStream_t stream)
{
  const float* x_in  = (const float*)d_in[0];
  const float* S     = (const float*)d_in[1];
  const float* B1    = (const float*)d_in[2];
  const float* B2    = (const float*)d_in[3];
  const float* Wv1   = (const float*)d_in[4];
  const float* Wout1 = (const float*)d_in[5];
  const float* Wv2   = (const float*)d_in[6];
  const float* Wout2 = (const float*)d_in[7];
  const int* idx1f   = (const int*)d_in[8];
  const int* idx1m   = (const int*)d_in[9];
  const int* idx2f   = (const int*)d_in[10];
  const int* idx2m   = (const int*)d_in[11];
  float* out = (float*)d_out;

  uint8_t* p = (uint8_t*)d_ws;
  auto alloc = [&](size_t bytes) -> void* {
    void* r = p;
    p += (bytes + 255) & ~(size_t)255;
    return r;
  };
  bf16*  SmIT = (bf16*)alloc((size_t)10 * NN * NN * sizeof(bf16));
  bf16*  B1T  = (bf16*)alloc((size_t)H1C * NN * sizeof(bf16));
  bf16*  B2T  = (bf16*)alloc((size_t)H2C * NN * sizeof(bf16));
  unsigned* cpack = (unsigned*)alloc((size_t)ROWS_TOTAL * CAP * sizeof(unsigned));
  int*   cnnz  = (int*)alloc((size_t)ROWS_TOTAL * sizeof(int));
  float* xf   = (float*)alloc((size_t)BATCH * NN * sizeof(float));
  bf16*  xb   = (bf16*)alloc((size_t)BATCH * NN * sizeof(bf16));
  unsigned short* tfT = (unsigned short*)alloc((size_t)NN * BATCH * sizeof(unsigned short)); // phi(x)
  float* chS  = (float*)alloc((size_t)BATCH * NN * sizeof(float));
  bf16*  chSb = (bf16*)alloc((size_t)BATCH * NN * sizeof(bf16));
  uint8_t* t1f8 = (uint8_t*)alloc((size_t)H2C * BATCH);                                       // fp8 t1
  uint8_t* t3f8 = (uint8_t*)alloc((size_t)H2C * BATCH);                                       // fp8 t3
  unsigned short* zTb = (unsigned short*)alloc((size_t)H2C * BATCH * sizeof(unsigned short)); // bf16 z
  unsigned short* gTb = (unsigned short*)alloc((size_t)H2C * BATCH * sizeof(unsigned short)); // bf16 g = Wv@t1
  unsigned short* t2p = (unsigned short*)alloc((size_t)H2C * BATCH * sizeof(unsigned short)); // phi(t2)
  float* xpT  = (float*)alloc((size_t)NN * BATCH * sizeof(float));
  (void)ws_size; (void)in_sizes; (void)n_in; (void)out_size;

  // --- per-call prep
  prep_smit<<<dim3(NN / 64, NN / 64, 10), 256, 0, stream>>>(S, SmIT);
  prep_bt<<<dim3(H1C / 64, NN / 64), 256, 0, stream>>>(B1, B1T, H1C);
  prep_bt<<<dim3(H2C / 64, NN / 64), 256, 0, stream>>>(B2, B2T, H2C);
  csr_build<<<5 * H1C, 256, 0, stream>>>(Wv1,   H1C, cpack, cnnz, ROW_WV1);
  csr_build<<<5 * NN,  256, 0, stream>>>(Wout1, H1C, cpack, cnnz, ROW_WO1);
  csr_build<<<5 * H2C, 256, 0, stream>>>(Wv2,   H2C, cpack, cnnz, ROW_WV2);
  csr_build<<<5 * NN,  256, 0, stream>>>(Wout2, H2C, cpack, cnnz, ROW_WO2);
  init_prep<<<dim3(NN / 64, BATCH / 64), 256, 0, stream>>>(x_in, xb, tfT);

  for (int k = 0; k < 10; ++k) {
    const bool g1 = (k % 2 == 0);
    const int j = k / 2;
    const int H = g1 ? H1C : H2C;
    const bf16* BmT = g1 ? B1T : B2T;
    const int* idf = g1 ? idx1f : idx2f;
    const int* idm = g1 ? idx1m : idx2m;
    const int wv_off = g1 ? (ROW_WV1 + j * H1C) : (ROW_WV2 + j * H2C);
    const int wo_off = g1 ? (ROW_WO1 + j * NN)  : (ROW_WO2 + j * NN);
    const float* xcur = (k == 0) ? x_in : xf;
    const int gb = (BATCH / 128) * (H / 128);   // z-GEMM blocks (bn fast, 16 wide)

    // L1: chS = x + x @ (S[k]-I)  ||  t1f8 = cn(tfT, idf)
    if (g1) chs_cn<6><<<CHS_GB + H, 256, 0, stream>>>(
        xb, SmIT + (size_t)k * NN * NN, chS, chSb, xcur, tfT, idf, t1f8);
    else    chs_cn<8><<<CHS_GB + H, 256, 0, stream>>>(
        xb, SmIT + (size_t)k * NN * NN, chS, chSb, xcur, tfT, idf, t1f8);
    // L2: zTb = bf16(BmT @ chS^T)  ||  gTb = bf16(Wv @ t1)
    zgemm_wv<<<gb + H, 256, 0, stream>>>(
        BmT, chSb, (bf16*)zTb, NN, gb, t1f8, cpack, cnnz, wv_off, gTb);
    // L3: t2p = phi( z + g )   (panel-pinned)
    phi_add_pin<<<dim3(NPAN, H / 4), 256, 0, stream>>>(zTb, gTb, t2p);
    // L4: t3f8 = cn(t2p, idm)  (panel-pinned)
    if (g1) cn_pin<6><<<dim3(NPAN, H / 4), 256, 0, stream>>>(t2p, idm, t3f8);
    else    cn_pin<8><<<dim3(NPAN, H / 4), 256, 0, stream>>>(t2p, idm, t3f8);
    // L5: xpT = Wout @ t3      (panel-pinned)
    wo_pin<<<dim3(NPAN, NN / 4), 256, 0, stream>>>(t3f8, cpack, cnnz, wo_off, xpT);
    // L6: epilogue
    fuse_out<<<dim3(NN / 64, BATCH / 64), 256, 0, stream>>>(
        xpT, chS, out + (size_t)k * BATCH * NN, xf, xb, tfT);
  }
}